// Round 1
// baseline (478.237 us; speedup 1.0000x reference)
//
#include <hip/hip_runtime.h>

#define B_ 32
#define K_ 1024
#define F_ 128
#define E_ 128
#define OUT2_ 125
#define ALPHA_ 0.2f

typedef __bf16 bf16x8_t __attribute__((ext_vector_type(8)));
typedef float  f32x4_t  __attribute__((ext_vector_type(4)));

__device__ __forceinline__ unsigned short f2bf(float f) {
    unsigned u = __float_as_uint(f);
    u = (u + 0x7fffu + ((u >> 16) & 1u)) >> 16;   // RNE
    return (unsigned short)u;
}

// ---------------- prep: w1 = lin_w^T a1, w2 = lin_w^T a2, c1/c2 = lin_b.a ----
__global__ void k_prep(const float* __restrict__ lin_w, const float* __restrict__ lin_b,
                       const float* __restrict__ a, float* __restrict__ ws) {
    int t = threadIdx.x;
    if (t < 128) {
        float acc = 0.f;
        for (int e = 0; e < E_; ++e) acc += lin_w[e * F_ + t] * a[e];
        ws[t] = acc;
    } else {
        int f = t - 128;
        float acc = 0.f;
        for (int e = 0; e < E_; ++e) acc += lin_w[e * F_ + f] * a[E_ + e];
        ws[128 + f] = acc;
    }
    if (t == 0) { float c = 0.f; for (int e = 0; e < E_; ++e) c += lin_b[e] * a[e];       ws[256] = c; }
    if (t == 1) { float c = 0.f; for (int e = 0; e < E_; ++e) c += lin_b[e] * a[E_ + e];  ws[257] = c; }
}

// ---------------- scores: one wave per (b,k) row -----------------------------
__global__ __launch_bounds__(256) void k_scores(const float* __restrict__ x,
                                                const float* __restrict__ ws,
                                                float* __restrict__ s1, float* __restrict__ s2) {
    int wave = threadIdx.x >> 6;
    int lane = threadIdx.x & 63;
    int row = blockIdx.x * 4 + wave;
    const float* xr = x + (size_t)row * F_;
    float x0 = xr[lane], x1 = xr[lane + 64];
    float p1 = x0 * ws[lane]       + x1 * ws[lane + 64];
    float p2 = x0 * ws[128 + lane] + x1 * ws[192 + lane];
    for (int m = 32; m; m >>= 1) { p1 += __shfl_xor(p1, m, 64); p2 += __shfl_xor(p2, m, 64); }
    if (lane == 0) { s1[row] = p1 + ws[256]; s2[row] = p2 + ws[257]; }
}

// ---------------- x transpose+cvt: xt[b][kt][f][kk], kt=K/64, kk in [0,64) ---
__global__ __launch_bounds__(256) void k_xt(const float* __restrict__ x,
                                            unsigned short* __restrict__ xt) {
    int kt = blockIdx.x;
    int b  = blockIdx.y;
    int t  = threadIdx.x;
    __shared__ float xs[64 * 132];
    const float* xb = x + ((size_t)b * K_ + kt * 64) * F_;
#pragma unroll
    for (int q = 0; q < 8; ++q) {
        int flat = q * 256 + t;
        int kk = flat >> 5, f4 = flat & 31;
        float4 v = *(const float4*)(xb + (size_t)kk * F_ + f4 * 4);
        xs[kk * 132 + f4 * 4]     = v.x;
        xs[kk * 132 + f4 * 4 + 1] = v.y;
        xs[kk * 132 + f4 * 4 + 2] = v.z;
        xs[kk * 132 + f4 * 4 + 3] = v.w;
    }
    __syncthreads();
    int f = t >> 1, half = t & 1;
    union { unsigned short u[32]; uint4 v[4]; } pack;
#pragma unroll
    for (int i = 0; i < 32; ++i) pack.u[i] = f2bf(xs[(half * 32 + i) * 132 + f]);
    unsigned short* dst = xt + (((size_t)(b * 16 + kt) * 128 + f) * 64 + half * 32);
    uint4* d4 = (uint4*)dst;
#pragma unroll
    for (int i = 0; i < 4; ++i) d4[i] = pack.v[i];
}

// ---------------- fused softmax + att@x  -------------------------------------
// Each block uniquely owns att rows [i0, i0+64) of batch b:
//   phase 0: row sums from s1/s2/bias (all L2-resident) -> rinv in LDS
//   main:    recompute e, write att fp32 (nontemporal, the only HBM stream),
//            feed bf16 e straight into MFMA. att never re-read from HBM.
// scores bounded (|s1|+|s2|+|bias| << 80), exp safe in fp32, no max pass.
__global__ __launch_bounds__(256) void k_attx(const float* __restrict__ s1,
                                              const float* __restrict__ s2,
                                              const float* __restrict__ bias,
                                              const unsigned short* __restrict__ xt,
                                              const float* __restrict__ x,
                                              float* __restrict__ att,
                                              unsigned short* __restrict__ h) {
    int b  = blockIdx.y;
    int i0 = blockIdx.x * 64;
    int t  = threadIdx.x;
    int wave = t >> 6, lane = t & 63;
    int quad = lane >> 4, l15 = lane & 15;

    __shared__ unsigned short A_s[64 * 72];    // 64i x 64k, pad 72
    __shared__ unsigned short X_s[128 * 72];   // 128f x 64k, pad 72
    __shared__ float rvs[64];

    int ai = t >> 2, aq = t & 3;               // 4 threads per row
    float sv = s1[b * K_ + i0 + ai];

    // ---- phase 0: row sums (each thread: cols where (idx4 % 4) == aq) ----
    const float4* s2r = (const float4*)(s2 + (size_t)b * K_);
    const float4* br  = (const float4*)(bias + (size_t)(i0 + ai) * K_);
    float sum = 0.f;
#pragma unroll 4
    for (int q = 0; q < 64; ++q) {
        float4 s2v = s2r[q * 4 + aq];
        float4 bv  = br[q * 4 + aq];
        float v;
        v = sv + s2v.x; v = v > 0.f ? v : ALPHA_ * v; sum += __expf(v + bv.x);
        v = sv + s2v.y; v = v > 0.f ? v : ALPHA_ * v; sum += __expf(v + bv.y);
        v = sv + s2v.z; v = v > 0.f ? v : ALPHA_ * v; sum += __expf(v + bv.z);
        v = sv + s2v.w; v = v > 0.f ? v : ALPHA_ * v; sum += __expf(v + bv.w);
    }
    sum += __shfl_xor(sum, 1, 64);
    sum += __shfl_xor(sum, 2, 64);
    if (aq == 0) rvs[ai] = 1.f / sum;

    f32x4_t acc[4][2];
#pragma unroll
    for (int m = 0; m < 4; ++m)
#pragma unroll
        for (int n = 0; n < 2; ++n) acc[m][n] = (f32x4_t)(0.f);

    int xf = t >> 1, xh = t & 1;

    for (int kt = 0; kt < 16; ++kt) {
        int k0 = kt * 64;
        __syncthreads();
        // A: recompute e tile, write att, pack bf16 -> LDS
        {
            int kb = k0 + aq * 16;
            float rv = rvs[ai];
            const float4* s2p = (const float4*)(s2 + (size_t)b * K_ + kb);
            const float4* bp  = (const float4*)(bias + (size_t)(i0 + ai) * K_ + kb);
            f32x4_t* ap = (f32x4_t*)(att + ((size_t)b * K_ + i0 + ai) * K_ + kb);
            union { unsigned short u[16]; uint4 v[2]; } p;
#pragma unroll
            for (int q = 0; q < 4; ++q) {
                float4 s2v = s2p[q];
                float4 bv  = bp[q];
                f32x4_t e;
                float v;
                v = sv + s2v.x; v = v > 0.f ? v : ALPHA_ * v; e[0] = __expf(v + bv.x) * rv;
                v = sv + s2v.y; v = v > 0.f ? v : ALPHA_ * v; e[1] = __expf(v + bv.y) * rv;
                v = sv + s2v.z; v = v > 0.f ? v : ALPHA_ * v; e[2] = __expf(v + bv.z) * rv;
                v = sv + s2v.w; v = v > 0.f ? v : ALPHA_ * v; e[3] = __expf(v + bv.w) * rv;
                __builtin_nontemporal_store(e, ap + q);
                p.u[q * 4]     = f2bf(e[0]);
                p.u[q * 4 + 1] = f2bf(e[1]);
                p.u[q * 4 + 2] = f2bf(e[2]);
                p.u[q * 4 + 3] = f2bf(e[3]);
            }
            uint4* d = (uint4*)&A_s[ai * 72 + aq * 16];
            d[0] = p.v[0]; d[1] = p.v[1];
        }
        // X: copy 16KB tile (bf16, f-major k-contig): 1024 uint4, 4/thread
        {
            const uint4* src = (const uint4*)(xt + ((size_t)(b * 16 + kt)) * 128 * 64) + t * 4;
            uint4* d = (uint4*)&X_s[xf * 72 + xh * 32];
#pragma unroll
            for (int q = 0; q < 4; ++q) d[q] = src[q];
        }
        __syncthreads();
#pragma unroll
        for (int kh = 0; kh < 2; ++kh) {
            bf16x8_t af[4], bff[2];
#pragma unroll
            for (int m = 0; m < 4; ++m)
                af[m] = *(const bf16x8_t*)&A_s[(m * 16 + l15) * 72 + kh * 32 + quad * 8];
#pragma unroll
            for (int n = 0; n < 2; ++n)
                bff[n] = *(const bf16x8_t*)&X_s[(wave * 32 + n * 16 + l15) * 72 + kh * 32 + quad * 8];
#pragma unroll
            for (int m = 0; m < 4; ++m)
#pragma unroll
                for (int n = 0; n < 2; ++n)
                    acc[m][n] = __builtin_amdgcn_mfma_f32_16x16x32_bf16(af[m], bff[n], acc[m][n], 0, 0, 0);
        }
    }
    // epilogue: h = bf16(acc + x residual)
#pragma unroll
    for (int m = 0; m < 4; ++m) {
#pragma unroll
        for (int n = 0; n < 2; ++n) {
            int f = wave * 32 + n * 16 + l15;
#pragma unroll
            for (int r = 0; r < 4; ++r) {
                int i = i0 + m * 16 + quad * 4 + r;
                size_t idx = ((size_t)b * K_ + i) * F_ + f;
                h[idx] = f2bf(acc[m][n][r] + x[idx]);
            }
        }
    }
}

// ---------------- out2 split-K partials: part[ks][b][f][o128] ----------------
__global__ __launch_bounds__(256) void k_out2p(const unsigned short* __restrict__ h,
                                               const float* __restrict__ w2,
                                               float* __restrict__ part) {
    int b  = blockIdx.y;
    int f0 = blockIdx.x * 16;
    int ks = blockIdx.z;
    int t = threadIdx.x;
    int o = t & 127;
    int g = t >> 7;
    __shared__ float hs[32 * 24];
    __shared__ float wt[128 * 33];
    const unsigned short* hb = h + (size_t)b * K_ * F_;
    float acc[8];
#pragma unroll
    for (int r = 0; r < 8; ++r) acc[r] = 0.f;

    int kbeg = ks * 256, kend = kbeg + 256;
    for (int k0 = kbeg; k0 < kend; k0 += 32) {
        {
            int idx = t * 2;
            int kk = idx >> 4, ff = idx & 15;
            unsigned pair = *(const unsigned*)(hb + (size_t)(k0 + kk) * F_ + f0 + ff);
            hs[kk * 24 + ff]     = __uint_as_float((pair & 0xFFFFu) << 16);
            hs[kk * 24 + ff + 1] = __uint_as_float((pair >> 16) << 16);
        }
#pragma unroll
        for (int q = 0; q < 16; ++q) {
            int idx = q * 256 + t;
            int oo = idx >> 5, kk = idx & 31;
            wt[oo * 33 + kk] = (oo < OUT2_) ? w2[(size_t)oo * K_ + k0 + kk] : 0.f;
        }
        __syncthreads();
#pragma unroll 8
        for (int kk = 0; kk < 32; ++kk) {
            float4 h0 = *(const float4*)&hs[kk * 24 + g * 8];
            float4 h1 = *(const float4*)&hs[kk * 24 + g * 8 + 4];
            float wv = wt[o * 33 + kk];
            acc[0] += h0.x * wv; acc[1] += h0.y * wv;
            acc[2] += h0.z * wv; acc[3] += h0.w * wv;
            acc[4] += h1.x * wv; acc[5] += h1.y * wv;
            acc[6] += h1.z * wv; acc[7] += h1.w * wv;
        }
        __syncthreads();
    }
#pragma unroll
    for (int r = 0; r < 8; ++r) {
        int f = f0 + g * 8 + r;
        part[((size_t)(ks * 32 + b) * 128 + f) * 128 + o] = acc[r];
    }
}

// ---------------- out2 epilogue: out = relu(sum_s part + b2) -----------------
__global__ __launch_bounds__(256) void k_out2e(const float* __restrict__ part,
                                               const float* __restrict__ b2,
                                               float* __restrict__ out) {
    int idx = blockIdx.x * 256 + threadIdx.x;           // over B*F*OUT2 = 512000
    if (idx >= B_ * F_ * OUT2_) return;
    int o  = idx % OUT2_;
    int bf = idx / OUT2_;                               // b*F + f, in [0, 4096)
    float v = b2[o];
#pragma unroll
    for (int s = 0; s < 4; ++s) v += part[((size_t)s * 4096 + bf) * 128 + o];
    out[idx] = v > 0.f ? v : 0.f;
}

extern "C" void kernel_launch(void* const* d_in, const int* in_sizes, int n_in,
                              void* d_out, int out_size, void* d_ws, size_t ws_size,
                              hipStream_t stream) {
    const float* x      = (const float*)d_in[0];
    const float* lin_w  = (const float*)d_in[1];
    const float* lin_b  = (const float*)d_in[2];
    const float* a      = (const float*)d_in[3];
    const float* bias   = (const float*)d_in[4];
    const float* lin2_w = (const float*)d_in[5];
    const float* lin2_b = (const float*)d_in[6];

    float* out = (float*)d_out;
    float* h2  = out;                                  // B*F*OUT2
    float* att = out + (size_t)B_ * F_ * OUT2_;        // B*K*K

    // ws: 258 prep | s1 32K | s2 32K | h bf16 8MB | xt bf16 8MB (reused as part)
    // total unchanged from round-1-proven footprint.
    float* ws = (float*)d_ws;
    float* s1 = ws + 512;
    float* s2 = ws + 512 + B_ * K_;
    unsigned short* h  = (unsigned short*)(ws + 512 + 2 * B_ * K_);   // B*K*F bf16
    unsigned short* xt = h + (size_t)B_ * K_ * F_;                    // B*K*F bf16
    float* part = (float*)xt;   // 4*32*128*128 floats = 8 MB; xt dead after k_attx

    k_prep<<<1, 256, 0, stream>>>(lin_w, lin_b, a, ws);
    k_scores<<<(B_ * K_) / 4, 256, 0, stream>>>(x, ws, s1, s2);
    k_xt<<<dim3(16, B_), 256, 0, stream>>>(x, xt);
    k_attx<<<dim3(K_ / 64, B_), 256, 0, stream>>>(s1, s2, bias, xt, x, att, h);
    k_out2p<<<dim3(F_ / 16, B_, 4), 256, 0, stream>>>(h, lin2_w, part);
    k_out2e<<<(B_ * F_ * OUT2_ + 255) / 256, 256, 0, stream>>>(part, lin2_b, h2);
}

// Round 2
// 330.691 us; speedup vs baseline: 1.4462x; 1.4462x over previous
//
#include <hip/hip_runtime.h>

#define B_ 32
#define K_ 1024
#define F_ 128
#define E_ 128
#define OUT2_ 125
#define ALPHA_ 0.2f

typedef __bf16 bf16x8_t __attribute__((ext_vector_type(8)));
typedef float  f32x4_t  __attribute__((ext_vector_type(4)));

__device__ __forceinline__ unsigned short f2bf(float f) {
    unsigned u = __float_as_uint(f);
    u = (u + 0x7fffu + ((u >> 16) & 1u)) >> 16;   // RNE
    return (unsigned short)u;
}

// ---------------- prep: w1 = lin_w^T a1, w2 = lin_w^T a2, c1/c2 = lin_b.a ----
__global__ void k_prep(const float* __restrict__ lin_w, const float* __restrict__ lin_b,
                       const float* __restrict__ a, float* __restrict__ ws) {
    int t = threadIdx.x;
    if (t < 128) {
        float acc = 0.f;
        for (int e = 0; e < E_; ++e) acc += lin_w[e * F_ + t] * a[e];
        ws[t] = acc;
    } else {
        int f = t - 128;
        float acc = 0.f;
        for (int e = 0; e < E_; ++e) acc += lin_w[e * F_ + f] * a[E_ + e];
        ws[128 + f] = acc;
    }
    if (t == 0) { float c = 0.f; for (int e = 0; e < E_; ++e) c += lin_b[e] * a[e];       ws[256] = c; }
    if (t == 1) { float c = 0.f; for (int e = 0; e < E_; ++e) c += lin_b[e] * a[E_ + e];  ws[257] = c; }
}

// ---------------- scores: one wave per (b,k) row -----------------------------
__global__ __launch_bounds__(256) void k_scores(const float* __restrict__ x,
                                                const float* __restrict__ ws,
                                                float* __restrict__ s1, float* __restrict__ s2) {
    int wave = threadIdx.x >> 6;
    int lane = threadIdx.x & 63;
    int row = blockIdx.x * 4 + wave;
    const float* xr = x + (size_t)row * F_;
    float x0 = xr[lane], x1 = xr[lane + 64];
    float p1 = x0 * ws[lane]       + x1 * ws[lane + 64];
    float p2 = x0 * ws[128 + lane] + x1 * ws[192 + lane];
    for (int m = 32; m; m >>= 1) { p1 += __shfl_xor(p1, m, 64); p2 += __shfl_xor(p2, m, 64); }
    if (lane == 0) { s1[row] = p1 + ws[256]; s2[row] = p2 + ws[257]; }
}

// ---------------- x transpose+cvt: xt[b][kt][f][kk], kt=K/64, kk in [0,64) ---
__global__ __launch_bounds__(256) void k_xt(const float* __restrict__ x,
                                            unsigned short* __restrict__ xt) {
    int kt = blockIdx.x;
    int b  = blockIdx.y;
    int t  = threadIdx.x;
    __shared__ float xs[64 * 132];
    const float* xb = x + ((size_t)b * K_ + kt * 64) * F_;
#pragma unroll
    for (int q = 0; q < 8; ++q) {
        int flat = q * 256 + t;
        int kk = flat >> 5, f4 = flat & 31;
        float4 v = *(const float4*)(xb + (size_t)kk * F_ + f4 * 4);
        xs[kk * 132 + f4 * 4]     = v.x;
        xs[kk * 132 + f4 * 4 + 1] = v.y;
        xs[kk * 132 + f4 * 4 + 2] = v.z;
        xs[kk * 132 + f4 * 4 + 3] = v.w;
    }
    __syncthreads();
    int f = t >> 1, half = t & 1;
    union { unsigned short u[32]; uint4 v[4]; } pack;
#pragma unroll
    for (int i = 0; i < 32; ++i) pack.u[i] = f2bf(xs[(half * 32 + i) * 132 + f]);
    unsigned short* dst = xt + (((size_t)(b * 16 + kt) * 128 + f) * 64 + half * 32);
    uint4* d4 = (uint4*)dst;
#pragma unroll
    for (int i = 0; i < 4; ++i) d4[i] = pack.v[i];
}

// ---------------- softmax: one block per (i,b) row, no max pass --------------
// Streaming att writer — dedicated kernel so the 128MB fp32 write runs at
// full occupancy / coalesced float4, with no barrier-drain interaction.
// scores bounded (|s1|+|s2|+|bias| << 80), exp safe in fp32; softmax invariant.
__global__ __launch_bounds__(256) void k_softmax(const float* __restrict__ s1,
                                                 const float* __restrict__ s2,
                                                 const float* __restrict__ bias,
                                                 float* __restrict__ att) {
    int i = blockIdx.x >> 5;
    int b = blockIdx.x & 31;
    int t = threadIdx.x;
    float sv = s1[b * K_ + i];
    float4 s2v = ((const float4*)(s2 + b * K_))[t];
    float4 bv  = ((const float4*)(bias + (size_t)i * K_))[t];
    float e[4];
    {
        float v;
        v = sv + s2v.x; v = v > 0.f ? v : ALPHA_ * v; e[0] = __expf(v + bv.x);
        v = sv + s2v.y; v = v > 0.f ? v : ALPHA_ * v; e[1] = __expf(v + bv.y);
        v = sv + s2v.z; v = v > 0.f ? v : ALPHA_ * v; e[2] = __expf(v + bv.z);
        v = sv + s2v.w; v = v > 0.f ? v : ALPHA_ * v; e[3] = __expf(v + bv.w);
    }
    float sum = e[0] + e[1] + e[2] + e[3];
    for (int m = 32; m; m >>= 1) sum += __shfl_xor(sum, m, 64);
    __shared__ float reds[4];
    int wave = t >> 6, lane = t & 63;
    if (lane == 0) reds[wave] = sum;
    __syncthreads();
    sum = reds[0] + reds[1] + reds[2] + reds[3];
    float r = 1.f / sum;
    float4 o; o.x = e[0] * r; o.y = e[1] * r; o.z = e[2] * r; o.w = e[3] * r;
    ((float4*)(att + ((size_t)b * K_ + i) * K_))[t] = o;
}

// ---------------- att@x via bf16 MFMA, A-tile recomputed (never read back) ---
// Each block owns rows [i0,i0+64) of batch b.  phase 0: row sums from
// s1/s2/bias (L2-resident) -> rinv in LDS.  Main loop: recompute
// e = exp(leaky(s1+s2)+bias)*rinv in registers, pack bf16 -> LDS, MFMA.
// NO global stores inside the barriered loop (round-1 lesson: the implicit
// vmcnt(0) drain before s_barrier serializes in-loop HBM stores).
__global__ __launch_bounds__(256) void k_attx(const float* __restrict__ s1,
                                              const float* __restrict__ s2,
                                              const float* __restrict__ bias,
                                              const unsigned short* __restrict__ xt,
                                              const float* __restrict__ x,
                                              unsigned short* __restrict__ h) {
    int b  = blockIdx.y;
    int i0 = blockIdx.x * 64;
    int t  = threadIdx.x;
    int wave = t >> 6, lane = t & 63;
    int quad = lane >> 4, l15 = lane & 15;

    __shared__ unsigned short A_s[64 * 72];    // 64i x 64k, pad 72
    __shared__ unsigned short X_s[128 * 72];   // 128f x 64k, pad 72
    __shared__ float rvs[64];

    int ai = t >> 2, aq = t & 3;               // 4 threads per row
    float sv = s1[b * K_ + i0 + ai];

    // ---- phase 0: row sums (each thread: float4 cols where idx4 % 4 == aq) --
    const float4* s2r = (const float4*)(s2 + (size_t)b * K_);
    const float4* br  = (const float4*)(bias + (size_t)(i0 + ai) * K_);
    float sum = 0.f;
#pragma unroll 4
    for (int q = 0; q < 64; ++q) {
        float4 s2v = s2r[q * 4 + aq];
        float4 bv  = br[q * 4 + aq];
        float v;
        v = sv + s2v.x; v = v > 0.f ? v : ALPHA_ * v; sum += __expf(v + bv.x);
        v = sv + s2v.y; v = v > 0.f ? v : ALPHA_ * v; sum += __expf(v + bv.y);
        v = sv + s2v.z; v = v > 0.f ? v : ALPHA_ * v; sum += __expf(v + bv.z);
        v = sv + s2v.w; v = v > 0.f ? v : ALPHA_ * v; sum += __expf(v + bv.w);
    }
    sum += __shfl_xor(sum, 1, 64);
    sum += __shfl_xor(sum, 2, 64);
    if (aq == 0) rvs[ai] = 1.f / sum;
    __syncthreads();
    float rv = rvs[ai];

    f32x4_t acc[4][2];
#pragma unroll
    for (int m = 0; m < 4; ++m)
#pragma unroll
        for (int n = 0; n < 2; ++n) acc[m][n] = (f32x4_t)(0.f);

    int xf = t >> 1, xh = t & 1;

    for (int kt = 0; kt < 16; ++kt) {
        int k0 = kt * 64;
        __syncthreads();
        // A: recompute e tile in registers, pack bf16 -> LDS (no global store)
        {
            int kb = k0 + aq * 16;
            const float4* s2p = (const float4*)(s2 + (size_t)b * K_ + kb);
            const float4* bp  = (const float4*)(bias + (size_t)(i0 + ai) * K_ + kb);
            union { unsigned short u[16]; uint4 v[2]; } p;
#pragma unroll
            for (int q = 0; q < 4; ++q) {
                float4 s2v = s2p[q];
                float4 bv  = bp[q];
                float v, e;
                v = sv + s2v.x; v = v > 0.f ? v : ALPHA_ * v; e = __expf(v + bv.x) * rv; p.u[q * 4]     = f2bf(e);
                v = sv + s2v.y; v = v > 0.f ? v : ALPHA_ * v; e = __expf(v + bv.y) * rv; p.u[q * 4 + 1] = f2bf(e);
                v = sv + s2v.z; v = v > 0.f ? v : ALPHA_ * v; e = __expf(v + bv.z) * rv; p.u[q * 4 + 2] = f2bf(e);
                v = sv + s2v.w; v = v > 0.f ? v : ALPHA_ * v; e = __expf(v + bv.w) * rv; p.u[q * 4 + 3] = f2bf(e);
            }
            uint4* d = (uint4*)&A_s[ai * 72 + aq * 16];
            d[0] = p.v[0]; d[1] = p.v[1];
        }
        // X: copy 16KB tile (bf16, f-major k-contig): 1024 uint4, 4/thread
        {
            const uint4* src = (const uint4*)(xt + ((size_t)(b * 16 + kt)) * 128 * 64) + t * 4;
            uint4* d = (uint4*)&X_s[xf * 72 + xh * 32];
#pragma unroll
            for (int q = 0; q < 4; ++q) d[q] = src[q];
        }
        __syncthreads();
#pragma unroll
        for (int kh = 0; kh < 2; ++kh) {
            bf16x8_t af[4], bff[2];
#pragma unroll
            for (int m = 0; m < 4; ++m)
                af[m] = *(const bf16x8_t*)&A_s[(m * 16 + l15) * 72 + kh * 32 + quad * 8];
#pragma unroll
            for (int n = 0; n < 2; ++n)
                bff[n] = *(const bf16x8_t*)&X_s[(wave * 32 + n * 16 + l15) * 72 + kh * 32 + quad * 8];
#pragma unroll
            for (int m = 0; m < 4; ++m)
#pragma unroll
                for (int n = 0; n < 2; ++n)
                    acc[m][n] = __builtin_amdgcn_mfma_f32_16x16x32_bf16(af[m], bff[n], acc[m][n], 0, 0, 0);
        }
    }
    // epilogue: h = bf16(acc + x residual)
#pragma unroll
    for (int m = 0; m < 4; ++m) {
#pragma unroll
        for (int n = 0; n < 2; ++n) {
            int f = wave * 32 + n * 16 + l15;
#pragma unroll
            for (int r = 0; r < 4; ++r) {
                int i = i0 + m * 16 + quad * 4 + r;
                size_t idx = ((size_t)b * K_ + i) * F_ + f;
                h[idx] = f2bf(acc[m][n][r] + x[idx]);
            }
        }
    }
}

// ---------------- out2 split-K partials: part[ks][b][f][o128] ----------------
__global__ __launch_bounds__(256) void k_out2p(const unsigned short* __restrict__ h,
                                               const float* __restrict__ w2,
                                               float* __restrict__ part) {
    int b  = blockIdx.y;
    int f0 = blockIdx.x * 16;
    int ks = blockIdx.z;
    int t = threadIdx.x;
    int o = t & 127;
    int g = t >> 7;
    __shared__ float hs[32 * 24];
    __shared__ float wt[128 * 33];
    const unsigned short* hb = h + (size_t)b * K_ * F_;
    float acc[8];
#pragma unroll
    for (int r = 0; r < 8; ++r) acc[r] = 0.f;

    int kbeg = ks * 256, kend = kbeg + 256;
    for (int k0 = kbeg; k0 < kend; k0 += 32) {
        {
            int idx = t * 2;
            int kk = idx >> 4, ff = idx & 15;
            unsigned pair = *(const unsigned*)(hb + (size_t)(k0 + kk) * F_ + f0 + ff);
            hs[kk * 24 + ff]     = __uint_as_float((pair & 0xFFFFu) << 16);
            hs[kk * 24 + ff + 1] = __uint_as_float((pair >> 16) << 16);
        }
#pragma unroll
        for (int q = 0; q < 16; ++q) {
            int idx = q * 256 + t;
            int oo = idx >> 5, kk = idx & 31;
            wt[oo * 33 + kk] = (oo < OUT2_) ? w2[(size_t)oo * K_ + k0 + kk] : 0.f;
        }
        __syncthreads();
#pragma unroll 8
        for (int kk = 0; kk < 32; ++kk) {
            float4 h0 = *(const float4*)&hs[kk * 24 + g * 8];
            float4 h1 = *(const float4*)&hs[kk * 24 + g * 8 + 4];
            float wv = wt[o * 33 + kk];
            acc[0] += h0.x * wv; acc[1] += h0.y * wv;
            acc[2] += h0.z * wv; acc[3] += h0.w * wv;
            acc[4] += h1.x * wv; acc[5] += h1.y * wv;
            acc[6] += h1.z * wv; acc[7] += h1.w * wv;
        }
        __syncthreads();
    }
#pragma unroll
    for (int r = 0; r < 8; ++r) {
        int f = f0 + g * 8 + r;
        part[((size_t)(ks * 32 + b) * 128 + f) * 128 + o] = acc[r];
    }
}

// ---------------- out2 epilogue: out = relu(sum_s part + b2) -----------------
__global__ __launch_bounds__(256) void k_out2e(const float* __restrict__ part,
                                               const float* __restrict__ b2,
                                               float* __restrict__ out) {
    int idx = blockIdx.x * 256 + threadIdx.x;           // over B*F*OUT2 = 512000
    if (idx >= B_ * F_ * OUT2_) return;
    int o  = idx % OUT2_;
    int bf = idx / OUT2_;                               // b*F + f, in [0, 4096)
    float v = b2[o];
#pragma unroll
    for (int s = 0; s < 4; ++s) v += part[((size_t)s * 4096 + bf) * 128 + o];
    out[idx] = v > 0.f ? v : 0.f;
}

extern "C" void kernel_launch(void* const* d_in, const int* in_sizes, int n_in,
                              void* d_out, int out_size, void* d_ws, size_t ws_size,
                              hipStream_t stream) {
    const float* x      = (const float*)d_in[0];
    const float* lin_w  = (const float*)d_in[1];
    const float* lin_b  = (const float*)d_in[2];
    const float* a      = (const float*)d_in[3];
    const float* bias   = (const float*)d_in[4];
    const float* lin2_w = (const float*)d_in[5];
    const float* lin2_b = (const float*)d_in[6];

    float* out = (float*)d_out;
    float* h2  = out;                                  // B*F*OUT2
    float* att = out + (size_t)B_ * F_ * OUT2_;        // B*K*K

    // ws: 258 prep | s1 32K | s2 32K | h bf16 8MB | xt bf16 8MB (reused as part)
    // total 17,041,408 B == round-1-proven footprint.
    float* ws = (float*)d_ws;
    float* s1 = ws + 512;
    float* s2 = ws + 512 + B_ * K_;
    unsigned short* h  = (unsigned short*)(ws + 512 + 2 * B_ * K_);   // B*K*F bf16
    unsigned short* xt = h + (size_t)B_ * K_ * F_;                    // B*K*F bf16
    float* part = (float*)xt;   // 4*32*128*128 floats = 8 MB; xt dead after k_attx

    k_prep<<<1, 256, 0, stream>>>(lin_w, lin_b, a, ws);
    k_scores<<<(B_ * K_) / 4, 256, 0, stream>>>(x, ws, s1, s2);
    k_xt<<<dim3(16, B_), 256, 0, stream>>>(x, xt);
    k_softmax<<<B_ * K_, 256, 0, stream>>>(s1, s2, bias, att);
    k_attx<<<dim3(K_ / 64, B_), 256, 0, stream>>>(s1, s2, bias, xt, x, h);
    k_out2p<<<dim3(F_ / 16, B_, 4), 256, 0, stream>>>(h, lin2_w, part);
    k_out2e<<<(B_ * F_ * OUT2_ + 255) / 256, 256, 0, stream>>>(part, lin2_b, h2);
}

// Round 3
// 293.760 us; speedup vs baseline: 1.6280x; 1.1257x over previous
//
#include <hip/hip_runtime.h>

#define B_ 32
#define K_ 1024
#define F_ 128
#define E_ 128
#define OUT2_ 125
#define ALPHA_ 0.2f

typedef __bf16 bf16x8_t __attribute__((ext_vector_type(8)));
typedef float  f32x4_t  __attribute__((ext_vector_type(4)));

__device__ __forceinline__ unsigned short f2bf(float f) {
    unsigned u = __float_as_uint(f);
    u = (u + 0x7fffu + ((u >> 16) & 1u)) >> 16;   // RNE
    return (unsigned short)u;
}

// ---------------- prep: w1 = lin_w^T a1, w2 = lin_w^T a2, c1/c2 = lin_b.a ----
__global__ void k_prep(const float* __restrict__ lin_w, const float* __restrict__ lin_b,
                       const float* __restrict__ a, float* __restrict__ ws) {
    int t = threadIdx.x;
    if (t < 128) {
        float acc = 0.f;
        for (int e = 0; e < E_; ++e) acc += lin_w[e * F_ + t] * a[e];
        ws[t] = acc;
    } else {
        int f = t - 128;
        float acc = 0.f;
        for (int e = 0; e < E_; ++e) acc += lin_w[e * F_ + f] * a[E_ + e];
        ws[128 + f] = acc;
    }
    if (t == 0) { float c = 0.f; for (int e = 0; e < E_; ++e) c += lin_b[e] * a[e];       ws[256] = c; }
    if (t == 1) { float c = 0.f; for (int e = 0; e < E_; ++e) c += lin_b[e] * a[E_ + e];  ws[257] = c; }
}

// ---------------- scores: one wave per (b,k) row -----------------------------
__global__ __launch_bounds__(256) void k_scores(const float* __restrict__ x,
                                                const float* __restrict__ ws,
                                                float* __restrict__ s1, float* __restrict__ s2) {
    int wave = threadIdx.x >> 6;
    int lane = threadIdx.x & 63;
    int row = blockIdx.x * 4 + wave;
    const float* xr = x + (size_t)row * F_;
    float x0 = xr[lane], x1 = xr[lane + 64];
    float p1 = x0 * ws[lane]       + x1 * ws[lane + 64];
    float p2 = x0 * ws[128 + lane] + x1 * ws[192 + lane];
    for (int m = 32; m; m >>= 1) { p1 += __shfl_xor(p1, m, 64); p2 += __shfl_xor(p2, m, 64); }
    if (lane == 0) { s1[row] = p1 + ws[256]; s2[row] = p2 + ws[257]; }
}

// ---------------- x transpose+cvt: xt[b][kt][f][kk], kt=K/64, kk in [0,64) ---
__global__ __launch_bounds__(256) void k_xt(const float* __restrict__ x,
                                            unsigned short* __restrict__ xt) {
    int kt = blockIdx.x;
    int b  = blockIdx.y;
    int t  = threadIdx.x;
    __shared__ float xs[64 * 132];
    const float* xb = x + ((size_t)b * K_ + kt * 64) * F_;
#pragma unroll
    for (int q = 0; q < 8; ++q) {
        int flat = q * 256 + t;
        int kk = flat >> 5, f4 = flat & 31;
        float4 v = *(const float4*)(xb + (size_t)kk * F_ + f4 * 4);
        xs[kk * 132 + f4 * 4]     = v.x;
        xs[kk * 132 + f4 * 4 + 1] = v.y;
        xs[kk * 132 + f4 * 4 + 2] = v.z;
        xs[kk * 132 + f4 * 4 + 3] = v.w;
    }
    __syncthreads();
    int f = t >> 1, half = t & 1;
    union { unsigned short u[32]; uint4 v[4]; } pack;
#pragma unroll
    for (int i = 0; i < 32; ++i) pack.u[i] = f2bf(xs[(half * 32 + i) * 132 + f]);
    unsigned short* dst = xt + (((size_t)(b * 16 + kt) * 128 + f) * 64 + half * 32);
    uint4* d4 = (uint4*)dst;
#pragma unroll
    for (int i = 0; i < 4; ++i) d4[i] = pack.v[i];
}

// ---------------- softmax: one block per (i,b) row, no max pass --------------
__global__ __launch_bounds__(256) void k_softmax(const float* __restrict__ s1,
                                                 const float* __restrict__ s2,
                                                 const float* __restrict__ bias,
                                                 float* __restrict__ att) {
    int i = blockIdx.x >> 5;
    int b = blockIdx.x & 31;
    int t = threadIdx.x;
    float sv = s1[b * K_ + i];
    float4 s2v = ((const float4*)(s2 + b * K_))[t];
    float4 bv  = ((const float4*)(bias + (size_t)i * K_))[t];
    float e[4];
    {
        float v;
        v = sv + s2v.x; v = v > 0.f ? v : ALPHA_ * v; e[0] = __expf(v + bv.x);
        v = sv + s2v.y; v = v > 0.f ? v : ALPHA_ * v; e[1] = __expf(v + bv.y);
        v = sv + s2v.z; v = v > 0.f ? v : ALPHA_ * v; e[2] = __expf(v + bv.z);
        v = sv + s2v.w; v = v > 0.f ? v : ALPHA_ * v; e[3] = __expf(v + bv.w);
    }
    float sum = e[0] + e[1] + e[2] + e[3];
    for (int m = 32; m; m >>= 1) sum += __shfl_xor(sum, m, 64);
    __shared__ float reds[4];
    int wave = t >> 6, lane = t & 63;
    if (lane == 0) reds[wave] = sum;
    __syncthreads();
    sum = reds[0] + reds[1] + reds[2] + reds[3];
    float r = 1.f / sum;
    float4 o; o.x = e[0] * r; o.y = e[1] * r; o.z = e[2] * r; o.w = e[3] * r;
    ((float4*)(att + ((size_t)b * K_ + i) * K_))[t] = o;
}

// ---------------- att@x via bf16 MFMA: 32i x 128f tile, grid 1024 ------------
// Round-3 changes vs proven round-0 kernel:
//  * i-tile 64 -> 32 rows: grid 512 -> 1024 = 4 blocks/CU (was grid-limited
//    at 2/CU, occupancy 21%). Latency chain per iter unchanged, 2x waves.
//  * output h stored TRANSPOSED: ht[b][f][k] bf16, so out2 can be a natural
//    MFMA GEMM (B operand f-rows k-contig). Lane holds 4 consecutive i -> 8B
//    packed stores.
// att is read back fp32 (L3-resident, round-2 lesson: recompute is slower).
__global__ __launch_bounds__(256) void k_attx(const float* __restrict__ att,
                                              const unsigned short* __restrict__ xt,
                                              const float* __restrict__ x,
                                              unsigned short* __restrict__ ht) {
    int b  = blockIdx.y;
    int i0 = blockIdx.x * 32;
    int t  = threadIdx.x;
    int wave = t >> 6, lane = t & 63;
    int quad = lane >> 4, l15 = lane & 15;

    __shared__ unsigned short A_s[32 * 72];    // 32i x 64k, pad 72
    __shared__ unsigned short X_s[128 * 72];   // 128f x 64k, pad 72

    const float* ab = att + ((size_t)b * K_ + i0) * K_;

    f32x4_t acc[2][2];
#pragma unroll
    for (int m = 0; m < 2; ++m)
#pragma unroll
        for (int n = 0; n < 2; ++n) acc[m][n] = (f32x4_t)(0.f);

    int ai = t >> 3, aq = t & 7;               // 32 rows, 8 threads/row
    int xf = t >> 1, xh = t & 1;

    for (int kt = 0; kt < 16; ++kt) {
        int k0 = kt * 64;
        __syncthreads();
        // A: 32x64 fp32 -> bf16 (2 float4 loads, 1 uint4 LDS write)
        {
            const float* src = ab + (size_t)ai * K_ + k0 + aq * 8;
            float4 v0 = *(const float4*)(src);
            float4 v1 = *(const float4*)(src + 4);
            union { unsigned short u[8]; uint4 v; } p;
            p.u[0] = f2bf(v0.x); p.u[1] = f2bf(v0.y); p.u[2] = f2bf(v0.z); p.u[3] = f2bf(v0.w);
            p.u[4] = f2bf(v1.x); p.u[5] = f2bf(v1.y); p.u[6] = f2bf(v1.z); p.u[7] = f2bf(v1.w);
            *(uint4*)&A_s[ai * 72 + aq * 8] = p.v;
        }
        // X: copy 16KB tile (bf16, f-major k-contig): 1024 uint4, 4/thread
        {
            const uint4* src = (const uint4*)(xt + ((size_t)(b * 16 + kt)) * 128 * 64) + t * 4;
            uint4* d = (uint4*)&X_s[xf * 72 + xh * 32];
#pragma unroll
            for (int q = 0; q < 4; ++q) d[q] = src[q];
        }
        __syncthreads();
#pragma unroll
        for (int kh = 0; kh < 2; ++kh) {
            bf16x8_t af[2], bff[2];
#pragma unroll
            for (int m = 0; m < 2; ++m)
                af[m] = *(const bf16x8_t*)&A_s[(m * 16 + l15) * 72 + kh * 32 + quad * 8];
#pragma unroll
            for (int n = 0; n < 2; ++n)
                bff[n] = *(const bf16x8_t*)&X_s[(wave * 32 + n * 16 + l15) * 72 + kh * 32 + quad * 8];
#pragma unroll
            for (int m = 0; m < 2; ++m)
#pragma unroll
                for (int n = 0; n < 2; ++n)
                    acc[m][n] = __builtin_amdgcn_mfma_f32_16x16x32_bf16(af[m], bff[n], acc[m][n], 0, 0, 0);
        }
    }
    // epilogue: ht[b][f][i] = bf16(acc + x residual), 8B packed along i
#pragma unroll
    for (int m = 0; m < 2; ++m) {
#pragma unroll
        for (int n = 0; n < 2; ++n) {
            int f = wave * 32 + n * 16 + l15;
            int ib = i0 + m * 16 + quad * 4;
            union { unsigned short u[4]; ushort4 v; } p;
#pragma unroll
            for (int r = 0; r < 4; ++r) {
                int i = ib + r;
                p.u[r] = f2bf(acc[m][n][r] + x[((size_t)b * K_ + i) * F_ + f]);
            }
            *(ushort4*)&ht[((size_t)b * F_ + f) * K_ + ib] = p.v;
        }
    }
}

// ---------------- out2 via MFMA: per (fh,b): C[o 128][f 64], K=1024 ----------
// A = w2 (o-rows k-contig, fp32->bf16 on the fly, rows >=125 zeroed)
// B = ht  (f-rows k-contig bf16). Epilogue: + b2, relu, scalar stores (OUT2=125
// makes rows unaligned for float4). Replaces k_out2p + part + k_out2e.
__global__ __launch_bounds__(256) void k_out2m(const unsigned short* __restrict__ ht,
                                               const float* __restrict__ w2,
                                               const float* __restrict__ b2,
                                               float* __restrict__ out) {
    int b  = blockIdx.y;
    int f0 = blockIdx.x * 64;
    int t  = threadIdx.x;
    int wave = t >> 6, lane = t & 63;
    int quad = lane >> 4, l15 = lane & 15;

    __shared__ unsigned short W_s[128 * 72];   // 128o x 64k
    __shared__ unsigned short H_s[64 * 72];    // 64f  x 64k

    f32x4_t acc[8];
#pragma unroll
    for (int m = 0; m < 8; ++m) acc[m] = (f32x4_t)(0.f);

    int wo = t >> 1, wq = t & 1;               // w2: 128 rows, 2 thr/row
    int hf = t >> 2, hq = t & 3;               // ht: 64 rows, 4 thr/row

    for (int kt = 0; kt < 16; ++kt) {
        int k0 = kt * 64;
        __syncthreads();
        // W: 128o x 64k fp32 -> bf16 (guard o>=125 -> 0)
        {
            union { unsigned short u[32]; uint4 v[4]; } p;
            if (wo < OUT2_) {
                const float* src = w2 + (size_t)wo * K_ + k0 + wq * 32;
#pragma unroll
                for (int q = 0; q < 8; ++q) {
                    float4 v = *(const float4*)(src + q * 4);
                    p.u[q * 4]     = f2bf(v.x);
                    p.u[q * 4 + 1] = f2bf(v.y);
                    p.u[q * 4 + 2] = f2bf(v.z);
                    p.u[q * 4 + 3] = f2bf(v.w);
                }
            } else {
#pragma unroll
                for (int q = 0; q < 4; ++q) p.v[q] = make_uint4(0, 0, 0, 0);
            }
            uint4* d = (uint4*)&W_s[wo * 72 + wq * 32];
#pragma unroll
            for (int q = 0; q < 4; ++q) d[q] = p.v[q];
        }
        // H: 64f x 64k bf16 copy (2 uint4/thread)
        {
            const uint4* src = (const uint4*)(ht + ((size_t)b * F_ + f0 + hf) * K_ + k0) + hq * 2;
            uint4* d = (uint4*)&H_s[hf * 72 + hq * 16];
            d[0] = src[0]; d[1] = src[1];
        }
        __syncthreads();
#pragma unroll
        for (int kh = 0; kh < 2; ++kh) {
            bf16x8_t bf = *(const bf16x8_t*)&H_s[(wave * 16 + l15) * 72 + kh * 32 + quad * 8];
#pragma unroll
            for (int m = 0; m < 8; ++m) {
                bf16x8_t af = *(const bf16x8_t*)&W_s[(m * 16 + l15) * 72 + kh * 32 + quad * 8];
                acc[m] = __builtin_amdgcn_mfma_f32_16x16x32_bf16(af, bf, acc[m], 0, 0, 0);
            }
        }
    }
    // epilogue: out[b][f][o] = relu(acc + b2[o]); D[m][n]: row=o, col(l15)=f
    int f = f0 + wave * 16 + l15;
    float* orow = out + ((size_t)b * F_ + f) * OUT2_;
#pragma unroll
    for (int m = 0; m < 8; ++m) {
        int ob = m * 16 + quad * 4;
#pragma unroll
        for (int r = 0; r < 4; ++r) {
            int o = ob + r;
            if (o < OUT2_) {
                float v = acc[m][r] + b2[o];
                orow[o] = v > 0.f ? v : 0.f;
            }
        }
    }
}

extern "C" void kernel_launch(void* const* d_in, const int* in_sizes, int n_in,
                              void* d_out, int out_size, void* d_ws, size_t ws_size,
                              hipStream_t stream) {
    const float* x      = (const float*)d_in[0];
    const float* lin_w  = (const float*)d_in[1];
    const float* lin_b  = (const float*)d_in[2];
    const float* a      = (const float*)d_in[3];
    const float* bias   = (const float*)d_in[4];
    const float* lin2_w = (const float*)d_in[5];
    const float* lin2_b = (const float*)d_in[6];

    float* out = (float*)d_out;
    float* h2  = out;                                  // B*F*OUT2
    float* att = out + (size_t)B_ * F_ * OUT2_;        // B*K*K

    // ws: 258 prep | s1 32K | s2 32K | ht bf16 8MB | xt bf16 8MB
    // total 17,041,408 B == proven footprint (ht replaces h byte-for-byte).
    float* ws = (float*)d_ws;
    float* s1 = ws + 512;
    float* s2 = ws + 512 + B_ * K_;
    unsigned short* ht = (unsigned short*)(ws + 512 + 2 * B_ * K_);   // B*F*K bf16
    unsigned short* xt = ht + (size_t)B_ * K_ * F_;                   // B*K*F bf16

    k_prep<<<1, 256, 0, stream>>>(lin_w, lin_b, a, ws);
    k_scores<<<(B_ * K_) / 4, 256, 0, stream>>>(x, ws, s1, s2);
    k_xt<<<dim3(16, B_), 256, 0, stream>>>(x, xt);
    k_softmax<<<B_ * K_, 256, 0, stream>>>(s1, s2, bias, att);
    k_attx<<<dim3(K_ / 32, B_), 256, 0, stream>>>(att, xt, x, ht);
    k_out2m<<<dim3(2, B_), 256, 0, stream>>>(ht, lin2_w, lin2_b, h2);
}

// Round 4
// 287.612 us; speedup vs baseline: 1.6628x; 1.0214x over previous
//
#include <hip/hip_runtime.h>

#define B_ 32
#define K_ 1024
#define F_ 128
#define E_ 128
#define OUT2_ 125
#define ALPHA_ 0.2f

typedef __bf16 bf16x8_t __attribute__((ext_vector_type(8)));
typedef float  f32x4_t  __attribute__((ext_vector_type(4)));

__device__ __forceinline__ unsigned short f2bf(float f) {
    unsigned u = __float_as_uint(f);
    u = (u + 0x7fffu + ((u >> 16) & 1u)) >> 16;   // RNE
    return (unsigned short)u;
}

// ---------------- prep: w1 = lin_w^T a1, w2 = lin_w^T a2, c1/c2 = lin_b.a ----
__global__ void k_prep(const float* __restrict__ lin_w, const float* __restrict__ lin_b,
                       const float* __restrict__ a, float* __restrict__ ws) {
    int t = threadIdx.x;
    if (t < 128) {
        float acc = 0.f;
        for (int e = 0; e < E_; ++e) acc += lin_w[e * F_ + t] * a[e];
        ws[t] = acc;
    } else {
        int f = t - 128;
        float acc = 0.f;
        for (int e = 0; e < E_; ++e) acc += lin_w[e * F_ + f] * a[E_ + e];
        ws[128 + f] = acc;
    }
    if (t == 0) { float c = 0.f; for (int e = 0; e < E_; ++e) c += lin_b[e] * a[e];       ws[256] = c; }
    if (t == 1) { float c = 0.f; for (int e = 0; e < E_; ++e) c += lin_b[e] * a[E_ + e];  ws[257] = c; }
}

// ---------------- scores: one wave per (b,k) row -----------------------------
__global__ __launch_bounds__(256) void k_scores(const float* __restrict__ x,
                                                const float* __restrict__ ws,
                                                float* __restrict__ s1, float* __restrict__ s2) {
    int wave = threadIdx.x >> 6;
    int lane = threadIdx.x & 63;
    int row = blockIdx.x * 4 + wave;
    const float* xr = x + (size_t)row * F_;
    float x0 = xr[lane], x1 = xr[lane + 64];
    float p1 = x0 * ws[lane]       + x1 * ws[lane + 64];
    float p2 = x0 * ws[128 + lane] + x1 * ws[192 + lane];
    for (int m = 32; m; m >>= 1) { p1 += __shfl_xor(p1, m, 64); p2 += __shfl_xor(p2, m, 64); }
    if (lane == 0) { s1[row] = p1 + ws[256]; s2[row] = p2 + ws[257]; }
}

// ---------------- x transpose+cvt: xt[b][kt][f][kk], kt=K/64, kk in [0,64) ---
__global__ __launch_bounds__(256) void k_xt(const float* __restrict__ x,
                                            unsigned short* __restrict__ xt) {
    int kt = blockIdx.x;
    int b  = blockIdx.y;
    int t  = threadIdx.x;
    __shared__ float xs[64 * 132];
    const float* xb = x + ((size_t)b * K_ + kt * 64) * F_;
#pragma unroll
    for (int q = 0; q < 8; ++q) {
        int flat = q * 256 + t;
        int kk = flat >> 5, f4 = flat & 31;
        float4 v = *(const float4*)(xb + (size_t)kk * F_ + f4 * 4);
        xs[kk * 132 + f4 * 4]     = v.x;
        xs[kk * 132 + f4 * 4 + 1] = v.y;
        xs[kk * 132 + f4 * 4 + 2] = v.z;
        xs[kk * 132 + f4 * 4 + 3] = v.w;
    }
    __syncthreads();
    int f = t >> 1, half = t & 1;
    union { unsigned short u[32]; uint4 v[4]; } pack;
#pragma unroll
    for (int i = 0; i < 32; ++i) pack.u[i] = f2bf(xs[(half * 32 + i) * 132 + f]);
    unsigned short* dst = xt + (((size_t)(b * 16 + kt) * 128 + f) * 64 + half * 32);
    uint4* d4 = (uint4*)dst;
#pragma unroll
    for (int i = 0; i < 4; ++i) d4[i] = pack.v[i];
}

// ---------------- softmax: one block per (i,b) row, no max pass --------------
__global__ __launch_bounds__(256) void k_softmax(const float* __restrict__ s1,
                                                 const float* __restrict__ s2,
                                                 const float* __restrict__ bias,
                                                 float* __restrict__ att) {
    int i = blockIdx.x >> 5;
    int b = blockIdx.x & 31;
    int t = threadIdx.x;
    float sv = s1[b * K_ + i];
    float4 s2v = ((const float4*)(s2 + b * K_))[t];
    float4 bv  = ((const float4*)(bias + (size_t)i * K_))[t];
    float e[4];
    {
        float v;
        v = sv + s2v.x; v = v > 0.f ? v : ALPHA_ * v; e[0] = __expf(v + bv.x);
        v = sv + s2v.y; v = v > 0.f ? v : ALPHA_ * v; e[1] = __expf(v + bv.y);
        v = sv + s2v.z; v = v > 0.f ? v : ALPHA_ * v; e[2] = __expf(v + bv.z);
        v = sv + s2v.w; v = v > 0.f ? v : ALPHA_ * v; e[3] = __expf(v + bv.w);
    }
    float sum = e[0] + e[1] + e[2] + e[3];
    for (int m = 32; m; m >>= 1) sum += __shfl_xor(sum, m, 64);
    __shared__ float reds[4];
    int wave = t >> 6, lane = t & 63;
    if (lane == 0) reds[wave] = sum;
    __syncthreads();
    sum = reds[0] + reds[1] + reds[2] + reds[3];
    float r = 1.f / sum;
    float4 o; o.x = e[0] * r; o.y = e[1] * r; o.z = e[2] * r; o.w = e[3] * r;
    ((float4*)(att + ((size_t)b * K_ + i) * K_))[t] = o;
}

// ---------------- att@x via bf16 MFMA: 32i x 128f, dbuf X, direct A ----------
// Round-4 changes:
//  * A (att) fragments loaded per-lane DIRECTLY from global (L1 absorbs the
//    4-wave redundancy; tile = 8KB fp32 << 32KB L1). No A LDS, no A staging.
//  * X tile double-buffered in LDS with XOR granule swizzle (gran ^= row&7):
//    uniform bank spread for both the flat staging writes and the b128
//    fragment reads, no padding -> 2x16KB = 32KB -> 4 blocks/CU.
//  * ONE barrier per iteration (dbuf write-after-read protected by the
//    previous barrier). Round-1 lesson: barrier drains are the cost; halve.
//  * X global loads lane-contiguous (1KB/wave segments, was 64B/lane stride).
__global__ __launch_bounds__(256, 4) void k_attx(const float* __restrict__ att,
                                                 const unsigned short* __restrict__ xt,
                                                 const float* __restrict__ x,
                                                 unsigned short* __restrict__ ht) {
    int b  = blockIdx.y;
    int i0 = blockIdx.x * 32;
    int t  = threadIdx.x;
    int wave = t >> 6, lane = t & 63;
    int quad = lane >> 4, l15 = lane & 15;

    __shared__ unsigned short X_s[2][128 * 64];   // swizzled, double-buffered

    const float* ab  = att + ((size_t)b * K_ + i0) * K_;
    const uint4* xtb = (const uint4*)(xt + (size_t)b * 16 * 128 * 64);

    f32x4_t acc[2][2];
#pragma unroll
    for (int m = 0; m < 2; ++m)
#pragma unroll
        for (int n = 0; n < 2; ++n) acc[m][n] = (f32x4_t)(0.f);

    // prologue: stage X tile 0 into buf 0
#pragma unroll
    for (int q = 0; q < 4; ++q) {
        int flat = q * 256 + t;
        int row = flat >> 3, g = flat & 7;
        *(uint4*)&X_s[0][row * 64 + 8 * (g ^ (row & 7))] = xtb[flat];
    }
    __syncthreads();

    int cur = 0;
    for (int kt = 0; kt < 16; ++kt) {
        int k0 = kt * 64;
        // issue next X tile loads (consumed after compute)
        uint4 xn[4];
        if (kt < 15) {
            const uint4* src = xtb + (size_t)(kt + 1) * 1024;
#pragma unroll
            for (int q = 0; q < 4; ++q) xn[q] = src[q * 256 + t];
        }
        // A fragments straight from att (fp32, L1-resident across waves)
        float4 av[2][2][2];
#pragma unroll
        for (int m = 0; m < 2; ++m) {
            const float* arow = ab + (size_t)(m * 16 + l15) * K_ + k0 + quad * 8;
#pragma unroll
            for (int kh = 0; kh < 2; ++kh) {
                av[m][kh][0] = *(const float4*)(arow + kh * 32);
                av[m][kh][1] = *(const float4*)(arow + kh * 32 + 4);
            }
        }
        // compute from buf[cur]
#pragma unroll
        for (int kh = 0; kh < 2; ++kh) {
            bf16x8_t af[2], bff[2];
#pragma unroll
            for (int m = 0; m < 2; ++m) {
                union { unsigned short u[8]; bf16x8_t v; } p;
                float4 v0 = av[m][kh][0], v1 = av[m][kh][1];
                p.u[0] = f2bf(v0.x); p.u[1] = f2bf(v0.y); p.u[2] = f2bf(v0.z); p.u[3] = f2bf(v0.w);
                p.u[4] = f2bf(v1.x); p.u[5] = f2bf(v1.y); p.u[6] = f2bf(v1.z); p.u[7] = f2bf(v1.w);
                af[m] = p.v;
            }
#pragma unroll
            for (int n = 0; n < 2; ++n) {
                int row = wave * 32 + n * 16 + l15;
                bff[n] = *(const bf16x8_t*)&X_s[cur][row * 64 + 8 * (((kh << 2) | quad) ^ (row & 7))];
            }
#pragma unroll
            for (int m = 0; m < 2; ++m)
#pragma unroll
                for (int n = 0; n < 2; ++n)
                    acc[m][n] = __builtin_amdgcn_mfma_f32_16x16x32_bf16(af[m], bff[n], acc[m][n], 0, 0, 0);
        }
        // write staged tile into buf[cur^1]
        if (kt < 15) {
#pragma unroll
            for (int q = 0; q < 4; ++q) {
                int flat = q * 256 + t;
                int row = flat >> 3, g = flat & 7;
                *(uint4*)&X_s[cur ^ 1][row * 64 + 8 * (g ^ (row & 7))] = xn[q];
            }
        }
        __syncthreads();
        cur ^= 1;
    }
    // epilogue: ht[b][f][i] = bf16(acc + x residual), 8B packed along i
#pragma unroll
    for (int m = 0; m < 2; ++m) {
#pragma unroll
        for (int n = 0; n < 2; ++n) {
            int f = wave * 32 + n * 16 + l15;
            int ib = i0 + m * 16 + quad * 4;
            union { unsigned short u[4]; ushort4 v; } p;
#pragma unroll
            for (int r = 0; r < 4; ++r) {
                int i = ib + r;
                p.u[r] = f2bf(acc[m][n][r] + x[((size_t)b * K_ + i) * F_ + f]);
            }
            *(ushort4*)&ht[((size_t)b * F_ + f) * K_ + ib] = p.v;
        }
    }
}

// ---------------- out2 MFMA split-K: per (fh,b,ks): C[o128][f64], K=256 ------
// Grid 64 -> 256 blocks (round-3 ran 64 blocks on 256 CUs). fp32 partials to
// the dead xt region; k_out2e reduces + bias + relu.
__global__ __launch_bounds__(256) void k_out2m(const unsigned short* __restrict__ ht,
                                               const float* __restrict__ w2,
                                               float* __restrict__ part) {
    int b  = blockIdx.y;
    int f0 = blockIdx.x * 64;
    int ks = blockIdx.z;
    int t  = threadIdx.x;
    int wave = t >> 6, lane = t & 63;
    int quad = lane >> 4, l15 = lane & 15;

    __shared__ unsigned short W_s[128 * 72];   // 128o x 64k
    __shared__ unsigned short H_s[64 * 72];    // 64f  x 64k

    f32x4_t acc[8];
#pragma unroll
    for (int m = 0; m < 8; ++m) acc[m] = (f32x4_t)(0.f);

    int wo = t >> 1, wq = t & 1;               // w2: 128 rows, 2 thr/row
    int hf = t >> 2, hq = t & 3;               // ht: 64 rows, 4 thr/row

    int kt0 = ks * 4;
    for (int kt = kt0; kt < kt0 + 4; ++kt) {
        int k0 = kt * 64;
        __syncthreads();
        // W: 128o x 64k fp32 -> bf16 (guard o>=125 -> 0)
        {
            union { unsigned short u[32]; uint4 v[4]; } p;
            if (wo < OUT2_) {
                const float* src = w2 + (size_t)wo * K_ + k0 + wq * 32;
#pragma unroll
                for (int q = 0; q < 8; ++q) {
                    float4 v = *(const float4*)(src + q * 4);
                    p.u[q * 4]     = f2bf(v.x);
                    p.u[q * 4 + 1] = f2bf(v.y);
                    p.u[q * 4 + 2] = f2bf(v.z);
                    p.u[q * 4 + 3] = f2bf(v.w);
                }
            } else {
#pragma unroll
                for (int q = 0; q < 4; ++q) p.v[q] = make_uint4(0, 0, 0, 0);
            }
            uint4* d = (uint4*)&W_s[wo * 72 + wq * 32];
#pragma unroll
            for (int q = 0; q < 4; ++q) d[q] = p.v[q];
        }
        // H: 64f x 64k bf16 copy (2 uint4/thread)
        {
            const uint4* src = (const uint4*)(ht + ((size_t)b * F_ + f0 + hf) * K_ + k0) + hq * 2;
            uint4* d = (uint4*)&H_s[hf * 72 + hq * 16];
            d[0] = src[0]; d[1] = src[1];
        }
        __syncthreads();
#pragma unroll
        for (int kh = 0; kh < 2; ++kh) {
            bf16x8_t bf = *(const bf16x8_t*)&H_s[(wave * 16 + l15) * 72 + kh * 32 + quad * 8];
#pragma unroll
            for (int m = 0; m < 8; ++m) {
                bf16x8_t af = *(const bf16x8_t*)&W_s[(m * 16 + l15) * 72 + kh * 32 + quad * 8];
                acc[m] = __builtin_amdgcn_mfma_f32_16x16x32_bf16(af, bf, acc[m], 0, 0, 0);
            }
        }
    }
    // partials: part[((ks*32+b)*128 + f)*128 + o], f32x4 along o
    int f = f0 + wave * 16 + l15;
    float* prow = part + ((size_t)(ks * 32 + b) * 128 + f) * 128;
#pragma unroll
    for (int m = 0; m < 8; ++m)
        *(f32x4_t*)&prow[m * 16 + quad * 4] = acc[m];
}

// ---------------- out2 epilogue: out = relu(sum_s part + b2) -----------------
__global__ __launch_bounds__(256) void k_out2e(const float* __restrict__ part,
                                               const float* __restrict__ b2,
                                               float* __restrict__ out) {
    int idx = blockIdx.x * 256 + threadIdx.x;           // over B*F*OUT2 = 512000
    if (idx >= B_ * F_ * OUT2_) return;
    int o  = idx % OUT2_;
    int bf = idx / OUT2_;                               // b*F + f, in [0, 4096)
    float v = b2[o];
#pragma unroll
    for (int s = 0; s < 4; ++s) v += part[((size_t)s * 4096 + bf) * 128 + o];
    out[idx] = v > 0.f ? v : 0.f;
}

extern "C" void kernel_launch(void* const* d_in, const int* in_sizes, int n_in,
                              void* d_out, int out_size, void* d_ws, size_t ws_size,
                              hipStream_t stream) {
    const float* x      = (const float*)d_in[0];
    const float* lin_w  = (const float*)d_in[1];
    const float* lin_b  = (const float*)d_in[2];
    const float* a      = (const float*)d_in[3];
    const float* bias   = (const float*)d_in[4];
    const float* lin2_w = (const float*)d_in[5];
    const float* lin2_b = (const float*)d_in[6];

    float* out = (float*)d_out;
    float* h2  = out;                                  // B*F*OUT2
    float* att = out + (size_t)B_ * F_ * OUT2_;        // B*K*K

    // ws: 258 prep | s1 32K | s2 32K | ht bf16 8MB | xt bf16 8MB (part reuse)
    // total 17,041,408 B == proven footprint.
    float* ws = (float*)d_ws;
    float* s1 = ws + 512;
    float* s2 = ws + 512 + B_ * K_;
    unsigned short* ht = (unsigned short*)(ws + 512 + 2 * B_ * K_);   // B*F*K bf16
    unsigned short* xt = ht + (size_t)B_ * K_ * F_;                   // B*K*F bf16
    float* part = (float*)xt;   // 4*32*128*128 floats = 8 MB; xt dead after k_attx

    k_prep<<<1, 256, 0, stream>>>(lin_w, lin_b, a, ws);
    k_scores<<<(B_ * K_) / 4, 256, 0, stream>>>(x, ws, s1, s2);
    k_xt<<<dim3(16, B_), 256, 0, stream>>>(x, xt);
    k_softmax<<<B_ * K_, 256, 0, stream>>>(s1, s2, bias, att);
    k_attx<<<dim3(K_ / 32, B_), 256, 0, stream>>>(att, xt, x, ht);
    k_out2m<<<dim3(2, B_, 4), 256, 0, stream>>>(ht, lin2_w, part);
    k_out2e<<<(B_ * F_ * OUT2_ + 255) / 256, 256, 0, stream>>>(part, lin2_b, h2);
}

// Round 5
// 283.609 us; speedup vs baseline: 1.6863x; 1.0141x over previous
//
#include <hip/hip_runtime.h>

#define B_ 32
#define K_ 1024
#define F_ 128
#define E_ 128
#define OUT2_ 125
#define ALPHA_ 0.2f

typedef __bf16 bf16x8_t __attribute__((ext_vector_type(8)));
typedef float  f32x4_t  __attribute__((ext_vector_type(4)));

// ---------------- prep: w1 = lin_w^T a1, w2 = lin_w^T a2, c1/c2 = lin_b.a ----
__global__ void k_prep(const float* __restrict__ lin_w, const float* __restrict__ lin_b,
                       const float* __restrict__ a, float* __restrict__ ws) {
    int t = threadIdx.x;
    if (t < 128) {
        float acc = 0.f;
        for (int e = 0; e < E_; ++e) acc += lin_w[e * F_ + t] * a[e];
        ws[t] = acc;
    } else {
        int f = t - 128;
        float acc = 0.f;
        for (int e = 0; e < E_; ++e) acc += lin_w[e * F_ + f] * a[E_ + e];
        ws[128 + f] = acc;
    }
    if (t == 0) { float c = 0.f; for (int e = 0; e < E_; ++e) c += lin_b[e] * a[e];       ws[256] = c; }
    if (t == 1) { float c = 0.f; for (int e = 0; e < E_; ++e) c += lin_b[e] * a[E_ + e];  ws[257] = c; }
}

// ------- x transpose+cvt + scores: xt[b][kt][f][kk] bf16, s1/s2 rows --------
// Round-5: k_scores fused in (both kernels read all of x; tile already in LDS).
// Native __bf16 casts (RNE in HW, compiler emits v_cvt_pk_bf16_f32) replace
// the 5-op manual f2bf.
__global__ __launch_bounds__(256) void k_xts(const float* __restrict__ x,
                                             const float* __restrict__ ws,
                                             unsigned short* __restrict__ xt,
                                             float* __restrict__ s1,
                                             float* __restrict__ s2) {
    int kt = blockIdx.x;
    int b  = blockIdx.y;
    int t  = threadIdx.x;
    __shared__ float xs[64 * 132];
    __shared__ float red1[4][64], red2[4][64];
    const float* xb = x + ((size_t)b * K_ + kt * 64) * F_;
#pragma unroll
    for (int q = 0; q < 8; ++q) {
        int flat = q * 256 + t;
        int kk = flat >> 5, f4 = flat & 31;
        float4 v = *(const float4*)(xb + (size_t)kk * F_ + f4 * 4);
        xs[kk * 132 + f4 * 4]     = v.x;
        xs[kk * 132 + f4 * 4 + 1] = v.y;
        xs[kk * 132 + f4 * 4 + 2] = v.z;
        xs[kk * 132 + f4 * 4 + 3] = v.w;
    }
    __syncthreads();
    // transpose-pack (bf16) — native casts
    {
        int f = t >> 1, half = t & 1;
        union { __bf16 h[32]; uint4 v[4]; } pack;
#pragma unroll
        for (int i = 0; i < 32; ++i) pack.h[i] = (__bf16)xs[(half * 32 + i) * 132 + f];
        unsigned short* dst = xt + (((size_t)(b * 16 + kt) * 128 + f) * 64 + half * 32);
        uint4* d4 = (uint4*)dst;
#pragma unroll
        for (int i = 0; i < 4; ++i) d4[i] = pack.v[i];
    }
    // scores: row r = t&63, f-segment p = t>>6 (32 f each), reduce via LDS
    {
        int r = t & 63, p = t >> 6;
        const float4* xr = (const float4*)&xs[r * 132 + p * 32];
        const float4* w1 = (const float4*)&ws[p * 32];
        const float4* w2 = (const float4*)&ws[128 + p * 32];
        float a1 = 0.f, a2 = 0.f;
#pragma unroll
        for (int q = 0; q < 8; ++q) {
            float4 xv = xr[q];
            float4 wa = w1[q], wb = w2[q];
            a1 += xv.x * wa.x + xv.y * wa.y + xv.z * wa.z + xv.w * wa.w;
            a2 += xv.x * wb.x + xv.y * wb.y + xv.z * wb.z + xv.w * wb.w;
        }
        red1[p][r] = a1; red2[p][r] = a2;
    }
    __syncthreads();
    if (t < 64) {
        s1[(size_t)b * K_ + kt * 64 + t] =
            red1[0][t] + red1[1][t] + red1[2][t] + red1[3][t] + ws[256];
    } else if (t < 128) {
        int r = t - 64;
        s2[(size_t)b * K_ + kt * 64 + r] =
            red2[0][r] + red2[1][r] + red2[2][r] + red2[3][r] + ws[257];
    }
}

// ---------------- softmax: one block per (i,b) row, no max pass --------------
__global__ __launch_bounds__(256) void k_softmax(const float* __restrict__ s1,
                                                 const float* __restrict__ s2,
                                                 const float* __restrict__ bias,
                                                 float* __restrict__ att) {
    int i = blockIdx.x >> 5;
    int b = blockIdx.x & 31;
    int t = threadIdx.x;
    float sv = s1[b * K_ + i];
    float4 s2v = ((const float4*)(s2 + b * K_))[t];
    float4 bv  = ((const float4*)(bias + (size_t)i * K_))[t];
    float e[4];
    {
        float v;
        v = sv + s2v.x; v = v > 0.f ? v : ALPHA_ * v; e[0] = __expf(v + bv.x);
        v = sv + s2v.y; v = v > 0.f ? v : ALPHA_ * v; e[1] = __expf(v + bv.y);
        v = sv + s2v.z; v = v > 0.f ? v : ALPHA_ * v; e[2] = __expf(v + bv.z);
        v = sv + s2v.w; v = v > 0.f ? v : ALPHA_ * v; e[3] = __expf(v + bv.w);
    }
    float sum = e[0] + e[1] + e[2] + e[3];
    for (int m = 32; m; m >>= 1) sum += __shfl_xor(sum, m, 64);
    __shared__ float reds[4];
    int wave = t >> 6, lane = t & 63;
    if (lane == 0) reds[wave] = sum;
    __syncthreads();
    sum = reds[0] + reds[1] + reds[2] + reds[3];
    float r = 1.f / sum;
    float4 o; o.x = e[0] * r; o.y = e[1] * r; o.z = e[2] * r; o.w = e[3] * r;
    ((float4*)(att + ((size_t)b * K_ + i) * K_))[t] = o;
}

// ---------------- att@x via bf16 MFMA: 32i x 128f, dbuf X, direct A ----------
// A fragments per-lane from global att (L1 absorbs 4-wave redundancy);
// X double-buffered, XOR-swizzled, one barrier/iter.
// Round-5: native __bf16 casts for the A-pack (was ~80 VALU ops/lane/iter
// of manual f2bf — the dominant compute term, bigger than the 8 MFMAs).
__global__ __launch_bounds__(256, 4) void k_attx(const float* __restrict__ att,
                                                 const unsigned short* __restrict__ xt,
                                                 const float* __restrict__ x,
                                                 unsigned short* __restrict__ ht) {
    int b  = blockIdx.y;
    int i0 = blockIdx.x * 32;
    int t  = threadIdx.x;
    int wave = t >> 6, lane = t & 63;
    int quad = lane >> 4, l15 = lane & 15;

    __shared__ unsigned short X_s[2][128 * 64];   // swizzled, double-buffered

    const float* ab  = att + ((size_t)b * K_ + i0) * K_;
    const uint4* xtb = (const uint4*)(xt + (size_t)b * 16 * 128 * 64);

    f32x4_t acc[2][2];
#pragma unroll
    for (int m = 0; m < 2; ++m)
#pragma unroll
        for (int n = 0; n < 2; ++n) acc[m][n] = (f32x4_t)(0.f);

    // prologue: stage X tile 0 into buf 0
#pragma unroll
    for (int q = 0; q < 4; ++q) {
        int flat = q * 256 + t;
        int row = flat >> 3, g = flat & 7;
        *(uint4*)&X_s[0][row * 64 + 8 * (g ^ (row & 7))] = xtb[flat];
    }
    __syncthreads();

    int cur = 0;
    for (int kt = 0; kt < 16; ++kt) {
        int k0 = kt * 64;
        // issue next X tile loads (consumed after compute)
        uint4 xn[4];
        if (kt < 15) {
            const uint4* src = xtb + (size_t)(kt + 1) * 1024;
#pragma unroll
            for (int q = 0; q < 4; ++q) xn[q] = src[q * 256 + t];
        }
        // A fragments straight from att (fp32, L1-resident across waves)
        float4 av[2][2][2];
#pragma unroll
        for (int m = 0; m < 2; ++m) {
            const float* arow = ab + (size_t)(m * 16 + l15) * K_ + k0 + quad * 8;
#pragma unroll
            for (int kh = 0; kh < 2; ++kh) {
                av[m][kh][0] = *(const float4*)(arow + kh * 32);
                av[m][kh][1] = *(const float4*)(arow + kh * 32 + 4);
            }
        }
        // compute from buf[cur]
#pragma unroll
        for (int kh = 0; kh < 2; ++kh) {
            bf16x8_t af[2], bff[2];
#pragma unroll
            for (int m = 0; m < 2; ++m) {
                union { __bf16 h[8]; bf16x8_t v; } p;
                float4 v0 = av[m][kh][0], v1 = av[m][kh][1];
                p.h[0] = (__bf16)v0.x; p.h[1] = (__bf16)v0.y;
                p.h[2] = (__bf16)v0.z; p.h[3] = (__bf16)v0.w;
                p.h[4] = (__bf16)v1.x; p.h[5] = (__bf16)v1.y;
                p.h[6] = (__bf16)v1.z; p.h[7] = (__bf16)v1.w;
                af[m] = p.v;
            }
#pragma unroll
            for (int n = 0; n < 2; ++n) {
                int row = wave * 32 + n * 16 + l15;
                bff[n] = *(const bf16x8_t*)&X_s[cur][row * 64 + 8 * (((kh << 2) | quad) ^ (row & 7))];
            }
#pragma unroll
            for (int m = 0; m < 2; ++m)
#pragma unroll
                for (int n = 0; n < 2; ++n)
                    acc[m][n] = __builtin_amdgcn_mfma_f32_16x16x32_bf16(af[m], bff[n], acc[m][n], 0, 0, 0);
        }
        // write staged tile into buf[cur^1]
        if (kt < 15) {
#pragma unroll
            for (int q = 0; q < 4; ++q) {
                int flat = q * 256 + t;
                int row = flat >> 3, g = flat & 7;
                *(uint4*)&X_s[cur ^ 1][row * 64 + 8 * (g ^ (row & 7))] = xn[q];
            }
        }
        __syncthreads();
        cur ^= 1;
    }
    // epilogue: ht[b][f][i] = bf16(acc + x residual), 8B packed along i
#pragma unroll
    for (int m = 0; m < 2; ++m) {
#pragma unroll
        for (int n = 0; n < 2; ++n) {
            int f = wave * 32 + n * 16 + l15;
            int ib = i0 + m * 16 + quad * 4;
            union { __bf16 h[4]; ushort4 v; } p;
#pragma unroll
            for (int r = 0; r < 4; ++r) {
                int i = ib + r;
                p.h[r] = (__bf16)(acc[m][n][r] + x[((size_t)b * K_ + i) * F_ + f]);
            }
            *(ushort4*)&ht[((size_t)b * F_ + f) * K_ + ib] = p.v;
        }
    }
}

// ---------------- out2 MFMA split-K: per (fh,b,ks): C[o128][f64], K=256 ------
__global__ __launch_bounds__(256) void k_out2m(const unsigned short* __restrict__ ht,
                                               const float* __restrict__ w2,
                                               float* __restrict__ part) {
    int b  = blockIdx.y;
    int f0 = blockIdx.x * 64;
    int ks = blockIdx.z;
    int t  = threadIdx.x;
    int wave = t >> 6, lane = t & 63;
    int quad = lane >> 4, l15 = lane & 15;

    __shared__ unsigned short W_s[128 * 72];   // 128o x 64k
    __shared__ unsigned short H_s[64 * 72];    // 64f  x 64k

    f32x4_t acc[8];
#pragma unroll
    for (int m = 0; m < 8; ++m) acc[m] = (f32x4_t)(0.f);

    int wo = t >> 1, wq = t & 1;               // w2: 128 rows, 2 thr/row
    int hf = t >> 2, hq = t & 3;               // ht: 64 rows, 4 thr/row

    int kt0 = ks * 4;
    for (int kt = kt0; kt < kt0 + 4; ++kt) {
        int k0 = kt * 64;
        __syncthreads();
        // W: 128o x 64k fp32 -> bf16 (guard o>=125 -> 0), native casts
        {
            union { __bf16 h[32]; uint4 v[4]; } p;
            if (wo < OUT2_) {
                const float* src = w2 + (size_t)wo * K_ + k0 + wq * 32;
#pragma unroll
                for (int q = 0; q < 8; ++q) {
                    float4 v = *(const float4*)(src + q * 4);
                    p.h[q * 4]     = (__bf16)v.x;
                    p.h[q * 4 + 1] = (__bf16)v.y;
                    p.h[q * 4 + 2] = (__bf16)v.z;
                    p.h[q * 4 + 3] = (__bf16)v.w;
                }
            } else {
#pragma unroll
                for (int q = 0; q < 4; ++q) p.v[q] = make_uint4(0, 0, 0, 0);
            }
            uint4* d = (uint4*)&W_s[wo * 72 + wq * 32];
#pragma unroll
            for (int q = 0; q < 4; ++q) d[q] = p.v[q];
        }
        // H: 64f x 64k bf16 copy (2 uint4/thread)
        {
            const uint4* src = (const uint4*)(ht + ((size_t)b * F_ + f0 + hf) * K_ + k0) + hq * 2;
            uint4* d = (uint4*)&H_s[hf * 72 + hq * 16];
            d[0] = src[0]; d[1] = src[1];
        }
        __syncthreads();
#pragma unroll
        for (int kh = 0; kh < 2; ++kh) {
            bf16x8_t bf = *(const bf16x8_t*)&H_s[(wave * 16 + l15) * 72 + kh * 32 + quad * 8];
#pragma unroll
            for (int m = 0; m < 8; ++m) {
                bf16x8_t af = *(const bf16x8_t*)&W_s[(m * 16 + l15) * 72 + kh * 32 + quad * 8];
                acc[m] = __builtin_amdgcn_mfma_f32_16x16x32_bf16(af, bf, acc[m], 0, 0, 0);
            }
        }
    }
    // partials: part[((ks*32+b)*128 + f)*128 + o], f32x4 along o
    int f = f0 + wave * 16 + l15;
    float* prow = part + ((size_t)(ks * 32 + b) * 128 + f) * 128;
#pragma unroll
    for (int m = 0; m < 8; ++m)
        *(f32x4_t*)&prow[m * 16 + quad * 4] = acc[m];
}

// ---------------- out2 epilogue: out = relu(sum_s part + b2) -----------------
__global__ __launch_bounds__(256) void k_out2e(const float* __restrict__ part,
                                               const float* __restrict__ b2,
                                               float* __restrict__ out) {
    int idx = blockIdx.x * 256 + threadIdx.x;           // over B*F*OUT2 = 512000
    if (idx >= B_ * F_ * OUT2_) return;
    int o  = idx % OUT2_;
    int bf = idx / OUT2_;                               // b*F + f, in [0, 4096)
    float v = b2[o];
#pragma unroll
    for (int s = 0; s < 4; ++s) v += part[((size_t)s * 4096 + bf) * 128 + o];
    out[idx] = v > 0.f ? v : 0.f;
}

extern "C" void kernel_launch(void* const* d_in, const int* in_sizes, int n_in,
                              void* d_out, int out_size, void* d_ws, size_t ws_size,
                              hipStream_t stream) {
    const float* x      = (const float*)d_in[0];
    const float* lin_w  = (const float*)d_in[1];
    const float* lin_b  = (const float*)d_in[2];
    const float* a      = (const float*)d_in[3];
    const float* bias   = (const float*)d_in[4];
    const float* lin2_w = (const float*)d_in[5];
    const float* lin2_b = (const float*)d_in[6];

    float* out = (float*)d_out;
    float* h2  = out;                                  // B*F*OUT2
    float* att = out + (size_t)B_ * F_ * OUT2_;        // B*K*K

    // ws: 258 prep | s1 32K | s2 32K | ht bf16 8MB | xt bf16 8MB (part reuse)
    // total 17,041,408 B == proven footprint.
    float* ws = (float*)d_ws;
    float* s1 = ws + 512;
    float* s2 = ws + 512 + B_ * K_;
    unsigned short* ht = (unsigned short*)(ws + 512 + 2 * B_ * K_);   // B*F*K bf16
    unsigned short* xt = ht + (size_t)B_ * K_ * F_;                   // B*K*F bf16
    float* part = (float*)xt;   // 4*32*128*128 floats = 8 MB; xt dead after k_attx

    k_prep<<<1, 256, 0, stream>>>(lin_w, lin_b, a, ws);
    k_xts<<<dim3(16, B_), 256, 0, stream>>>(x, ws, xt, s1, s2);
    k_softmax<<<B_ * K_, 256, 0, stream>>>(s1, s2, bias, att);
    k_attx<<<dim3(K_ / 32, B_), 256, 0, stream>>>(att, xt, x, ht);
    k_out2m<<<dim3(2, B_, 4), 256, 0, stream>>>(ht, lin2_w, part);
    k_out2e<<<(B_ * F_ * OUT2_ + 255) / 256, 256, 0, stream>>>(part, lin2_b, h2);
}

// Round 6
// 280.108 us; speedup vs baseline: 1.7073x; 1.0125x over previous
//
#include <hip/hip_runtime.h>

#define B_ 32
#define K_ 1024
#define F_ 128
#define E_ 128
#define OUT2_ 125
#define ALPHA_ 0.2f

typedef __bf16 bf16x8_t __attribute__((ext_vector_type(8)));
typedef float  f32x4_t  __attribute__((ext_vector_type(4)));

// ------- x transpose+cvt + scores + (fused) prep ----------------------------
// Round-6: k_prep folded in — every block computes ws (w1=lin_w^T a1,
// w2=lin_w^T a2, c1/c2=lin_b.a) into LDS. lin_w column reads are
// lane-coalesced (lane f reads lin_w[e*128+f], 256B/wave/e), L2-hot after the
// first blocks. Removes one dispatch + its gap and the ws global round-trip.
__global__ __launch_bounds__(256) void k_xts(const float* __restrict__ x,
                                             const float* __restrict__ lin_w,
                                             const float* __restrict__ lin_b,
                                             const float* __restrict__ a,
                                             unsigned short* __restrict__ xt,
                                             float* __restrict__ s1,
                                             float* __restrict__ s2) {
    int kt = blockIdx.x;
    int b  = blockIdx.y;
    int t  = threadIdx.x;
    __shared__ float xs[64 * 132];
    __shared__ float red1[4][64], red2[4][64];
    __shared__ float wsl[260];

    // ws: waves 0-1 -> a1 path (f = t), waves 2-3 -> a2 path
    {
        int f = t & 127, sel = t >> 7;
        const float* av = a + sel * 128;
        float acc = 0.f;
#pragma unroll 8
        for (int e = 0; e < E_; ++e) acc += lin_w[e * F_ + f] * av[e];
        wsl[sel * 128 + f] = acc;
        if (t < 2) {
            const float* aw = a + t * 128;
            float c = 0.f;
#pragma unroll 8
            for (int e = 0; e < E_; ++e) c += lin_b[e] * aw[e];
            wsl[256 + t] = c;
        }
    }
    const float* xb = x + ((size_t)b * K_ + kt * 64) * F_;
#pragma unroll
    for (int q = 0; q < 8; ++q) {
        int flat = q * 256 + t;
        int kk = flat >> 5, f4 = flat & 31;
        float4 v = *(const float4*)(xb + (size_t)kk * F_ + f4 * 4);
        xs[kk * 132 + f4 * 4]     = v.x;
        xs[kk * 132 + f4 * 4 + 1] = v.y;
        xs[kk * 132 + f4 * 4 + 2] = v.z;
        xs[kk * 132 + f4 * 4 + 3] = v.w;
    }
    __syncthreads();
    // transpose-pack (bf16) — native casts
    {
        int f = t >> 1, half = t & 1;
        union { __bf16 h[32]; uint4 v[4]; } pack;
#pragma unroll
        for (int i = 0; i < 32; ++i) pack.h[i] = (__bf16)xs[(half * 32 + i) * 132 + f];
        unsigned short* dst = xt + (((size_t)(b * 16 + kt) * 128 + f) * 64 + half * 32);
        uint4* d4 = (uint4*)dst;
#pragma unroll
        for (int i = 0; i < 4; ++i) d4[i] = pack.v[i];
    }
    // scores: row r = t&63, f-segment p = t>>6 (32 f each), reduce via LDS
    {
        int r = t & 63, p = t >> 6;
        const float4* xr = (const float4*)&xs[r * 132 + p * 32];
        const float4* w1 = (const float4*)&wsl[p * 32];
        const float4* w2 = (const float4*)&wsl[128 + p * 32];
        float a1 = 0.f, a2 = 0.f;
#pragma unroll
        for (int q = 0; q < 8; ++q) {
            float4 xv = xr[q];
            float4 wa = w1[q], wb = w2[q];
            a1 += xv.x * wa.x + xv.y * wa.y + xv.z * wa.z + xv.w * wa.w;
            a2 += xv.x * wb.x + xv.y * wb.y + xv.z * wb.z + xv.w * wb.w;
        }
        red1[p][r] = a1; red2[p][r] = a2;
    }
    __syncthreads();
    if (t < 64) {
        s1[(size_t)b * K_ + kt * 64 + t] =
            red1[0][t] + red1[1][t] + red1[2][t] + red1[3][t] + wsl[256];
    } else if (t < 128) {
        int r = t - 64;
        s2[(size_t)b * K_ + kt * 64 + r] =
            red2[0][r] + red2[1][r] + red2[2][r] + red2[3][r] + wsl[257];
    }
}

// ---------------- softmax: one block per (i,b) row, no max pass --------------
__global__ __launch_bounds__(256) void k_softmax(const float* __restrict__ s1,
                                                 const float* __restrict__ s2,
                                                 const float* __restrict__ bias,
                                                 float* __restrict__ att) {
    int i = blockIdx.x >> 5;
    int b = blockIdx.x & 31;
    int t = threadIdx.x;
    float sv = s1[b * K_ + i];
    float4 s2v = ((const float4*)(s2 + b * K_))[t];
    float4 bv  = ((const float4*)(bias + (size_t)i * K_))[t];
    float e[4];
    {
        float v;
        v = sv + s2v.x; v = v > 0.f ? v : ALPHA_ * v; e[0] = __expf(v + bv.x);
        v = sv + s2v.y; v = v > 0.f ? v : ALPHA_ * v; e[1] = __expf(v + bv.y);
        v = sv + s2v.z; v = v > 0.f ? v : ALPHA_ * v; e[2] = __expf(v + bv.z);
        v = sv + s2v.w; v = v > 0.f ? v : ALPHA_ * v; e[3] = __expf(v + bv.w);
    }
    float sum = e[0] + e[1] + e[2] + e[3];
    for (int m = 32; m; m >>= 1) sum += __shfl_xor(sum, m, 64);
    __shared__ float reds[4];
    int wave = t >> 6, lane = t & 63;
    if (lane == 0) reds[wave] = sum;
    __syncthreads();
    sum = reds[0] + reds[1] + reds[2] + reds[3];
    float r = 1.f / sum;
    float4 o; o.x = e[0] * r; o.y = e[1] * r; o.z = e[2] * r; o.w = e[3] * r;
    ((float4*)(att + ((size_t)b * K_ + i) * K_))[t] = o;
}

// ---------------- att@x via bf16 MFMA: 32i x 128f, dbuf X, pipelined A -------
// Round-6: A fragments register-double-buffered across iterations. Loads for
// tile kt+1 are issued right after the barrier; the bf16 cvt happens after the
// MFMAs of tile kt are issued — the ~200-300cy L2 latency hides under the
// MFMA + LDS work instead of sitting on the post-barrier critical path (the
// round-4/5 structure consumed A immediately after loading it each iter).
// Full unroll so the afc double-buffer is register-renamed (rule: static idx).
__global__ __launch_bounds__(256, 4) void k_attx(const float* __restrict__ att,
                                                 const unsigned short* __restrict__ xt,
                                                 const float* __restrict__ x,
                                                 unsigned short* __restrict__ ht) {
    int b  = blockIdx.y;
    int i0 = blockIdx.x * 32;
    int t  = threadIdx.x;
    int wave = t >> 6, lane = t & 63;
    int quad = lane >> 4, l15 = lane & 15;

    __shared__ unsigned short X_s[2][128 * 64];   // swizzled, double-buffered

    const float* ab  = att + ((size_t)b * K_ + i0) * K_;
    const uint4* xtb = (const uint4*)(xt + (size_t)b * 16 * 128 * 64);

    const float* arow[2];
    arow[0] = ab + (size_t)l15 * K_ + quad * 8;
    arow[1] = arow[0] + 16 * K_;

    f32x4_t acc[2][2];
#pragma unroll
    for (int m = 0; m < 2; ++m)
#pragma unroll
        for (int n = 0; n < 2; ++n) acc[m][n] = (f32x4_t)(0.f);

    bf16x8_t afc[2][2];
    // prologue: issue A0 loads, stage X0 into buf 0, cvt A0
    {
        float4 av[2][2][2];
#pragma unroll
        for (int m = 0; m < 2; ++m)
#pragma unroll
            for (int kh = 0; kh < 2; ++kh) {
                av[m][kh][0] = *(const float4*)(arow[m] + kh * 32);
                av[m][kh][1] = *(const float4*)(arow[m] + kh * 32 + 4);
            }
#pragma unroll
        for (int q = 0; q < 4; ++q) {
            int flat = q * 256 + t;
            int row = flat >> 3, g = flat & 7;
            *(uint4*)&X_s[0][row * 64 + 8 * (g ^ (row & 7))] = xtb[flat];
        }
#pragma unroll
        for (int m = 0; m < 2; ++m)
#pragma unroll
            for (int kh = 0; kh < 2; ++kh) {
                union { __bf16 h[8]; bf16x8_t v; } p;
                float4 v0 = av[m][kh][0], v1 = av[m][kh][1];
                p.h[0] = (__bf16)v0.x; p.h[1] = (__bf16)v0.y;
                p.h[2] = (__bf16)v0.z; p.h[3] = (__bf16)v0.w;
                p.h[4] = (__bf16)v1.x; p.h[5] = (__bf16)v1.y;
                p.h[6] = (__bf16)v1.z; p.h[7] = (__bf16)v1.w;
                afc[m][kh] = p.v;
            }
    }
    __syncthreads();

    int cur = 0;
#pragma unroll
    for (int kt = 0; kt < 16; ++kt) {
        uint4 xn[4];
        float4 av[2][2][2];
        if (kt < 15) {
            // issue next X + next A loads (consumed after the MFMAs below)
            const uint4* src = xtb + (size_t)(kt + 1) * 1024;
#pragma unroll
            for (int q = 0; q < 4; ++q) xn[q] = src[q * 256 + t];
            int ko = (kt + 1) * 64;
#pragma unroll
            for (int m = 0; m < 2; ++m)
#pragma unroll
                for (int kh = 0; kh < 2; ++kh) {
                    av[m][kh][0] = *(const float4*)(arow[m] + ko + kh * 32);
                    av[m][kh][1] = *(const float4*)(arow[m] + ko + kh * 32 + 4);
                }
        }
        // MFMAs for tile kt from afc + X_s[cur]
#pragma unroll
        for (int kh = 0; kh < 2; ++kh) {
            bf16x8_t bff[2];
#pragma unroll
            for (int n = 0; n < 2; ++n) {
                int row = wave * 32 + n * 16 + l15;
                bff[n] = *(const bf16x8_t*)&X_s[cur][row * 64 + 8 * (((kh << 2) | quad) ^ (row & 7))];
            }
#pragma unroll
            for (int m = 0; m < 2; ++m)
#pragma unroll
                for (int n = 0; n < 2; ++n)
                    acc[m][n] = __builtin_amdgcn_mfma_f32_16x16x32_bf16(afc[m][kh], bff[n], acc[m][n], 0, 0, 0);
        }
        if (kt < 15) {
            // cvt next A into afc (after MFMA issue — latency hidden)
#pragma unroll
            for (int m = 0; m < 2; ++m)
#pragma unroll
                for (int kh = 0; kh < 2; ++kh) {
                    union { __bf16 h[8]; bf16x8_t v; } p;
                    float4 v0 = av[m][kh][0], v1 = av[m][kh][1];
                    p.h[0] = (__bf16)v0.x; p.h[1] = (__bf16)v0.y;
                    p.h[2] = (__bf16)v0.z; p.h[3] = (__bf16)v0.w;
                    p.h[4] = (__bf16)v1.x; p.h[5] = (__bf16)v1.y;
                    p.h[6] = (__bf16)v1.z; p.h[7] = (__bf16)v1.w;
                    afc[m][kh] = p.v;
                }
            // stage next X into buf[cur^1]
#pragma unroll
            for (int q = 0; q < 4; ++q) {
                int flat = q * 256 + t;
                int row = flat >> 3, g = flat & 7;
                *(uint4*)&X_s[cur ^ 1][row * 64 + 8 * (g ^ (row & 7))] = xn[q];
            }
        }
        __syncthreads();
        cur ^= 1;
    }
    // epilogue: ht[b][f][i] = bf16(acc + x residual), 8B packed along i
#pragma unroll
    for (int m = 0; m < 2; ++m) {
#pragma unroll
        for (int n = 0; n < 2; ++n) {
            int f = wave * 32 + n * 16 + l15;
            int ib = i0 + m * 16 + quad * 4;
            union { __bf16 h[4]; ushort4 v; } p;
#pragma unroll
            for (int r = 0; r < 4; ++r) {
                int i = ib + r;
                p.h[r] = (__bf16)(acc[m][n][r] + x[((size_t)b * K_ + i) * F_ + f]);
            }
            *(ushort4*)&ht[((size_t)b * F_ + f) * K_ + ib] = p.v;
        }
    }
}

// ---------------- out2 MFMA split-K: per (fh,b,ks): C[o128][f64], K=256 ------
__global__ __launch_bounds__(256) void k_out2m(const unsigned short* __restrict__ ht,
                                               const float* __restrict__ w2,
                                               float* __restrict__ part) {
    int b  = blockIdx.y;
    int f0 = blockIdx.x * 64;
    int ks = blockIdx.z;
    int t  = threadIdx.x;
    int wave = t >> 6, lane = t & 63;
    int quad = lane >> 4, l15 = lane & 15;

    __shared__ unsigned short W_s[128 * 72];   // 128o x 64k
    __shared__ unsigned short H_s[64 * 72];    // 64f  x 64k

    f32x4_t acc[8];
#pragma unroll
    for (int m = 0; m < 8; ++m) acc[m] = (f32x4_t)(0.f);

    int wo = t >> 1, wq = t & 1;               // w2: 128 rows, 2 thr/row
    int hf = t >> 2, hq = t & 3;               // ht: 64 rows, 4 thr/row

    int kt0 = ks * 4;
    for (int kt = kt0; kt < kt0 + 4; ++kt) {
        int k0 = kt * 64;
        __syncthreads();
        // W: 128o x 64k fp32 -> bf16 (guard o>=125 -> 0), native casts
        {
            union { __bf16 h[32]; uint4 v[4]; } p;
            if (wo < OUT2_) {
                const float* src = w2 + (size_t)wo * K_ + k0 + wq * 32;
#pragma unroll
                for (int q = 0; q < 8; ++q) {
                    float4 v = *(const float4*)(src + q * 4);
                    p.h[q * 4]     = (__bf16)v.x;
                    p.h[q * 4 + 1] = (__bf16)v.y;
                    p.h[q * 4 + 2] = (__bf16)v.z;
                    p.h[q * 4 + 3] = (__bf16)v.w;
                }
            } else {
#pragma unroll
                for (int q = 0; q < 4; ++q) p.v[q] = make_uint4(0, 0, 0, 0);
            }
            uint4* d = (uint4*)&W_s[wo * 72 + wq * 32];
#pragma unroll
            for (int q = 0; q < 4; ++q) d[q] = p.v[q];
        }
        // H: 64f x 64k bf16 copy (2 uint4/thread)
        {
            const uint4* src = (const uint4*)(ht + ((size_t)b * F_ + f0 + hf) * K_ + k0) + hq * 2;
            uint4* d = (uint4*)&H_s[hf * 72 + hq * 16];
            d[0] = src[0]; d[1] = src[1];
        }
        __syncthreads();
#pragma unroll
        for (int kh = 0; kh < 2; ++kh) {
            bf16x8_t bf = *(const bf16x8_t*)&H_s[(wave * 16 + l15) * 72 + kh * 32 + quad * 8];
#pragma unroll
            for (int m = 0; m < 8; ++m) {
                bf16x8_t af = *(const bf16x8_t*)&W_s[(m * 16 + l15) * 72 + kh * 32 + quad * 8];
                acc[m] = __builtin_amdgcn_mfma_f32_16x16x32_bf16(af, bf, acc[m], 0, 0, 0);
            }
        }
    }
    // partials: part[((ks*32+b)*128 + f)*128 + o], f32x4 along o
    int f = f0 + wave * 16 + l15;
    float* prow = part + ((size_t)(ks * 32 + b) * 128 + f) * 128;
#pragma unroll
    for (int m = 0; m < 8; ++m)
        *(f32x4_t*)&prow[m * 16 + quad * 4] = acc[m];
}

// ---------------- out2 epilogue: out = relu(sum_s part + b2) -----------------
__global__ __launch_bounds__(256) void k_out2e(const float* __restrict__ part,
                                               const float* __restrict__ b2,
                                               float* __restrict__ out) {
    int idx = blockIdx.x * 256 + threadIdx.x;           // over B*F*OUT2 = 512000
    if (idx >= B_ * F_ * OUT2_) return;
    int o  = idx % OUT2_;
    int bf = idx / OUT2_;                               // b*F + f, in [0, 4096)
    float v = b2[o];
#pragma unroll
    for (int s = 0; s < 4; ++s) v += part[((size_t)s * 4096 + bf) * 128 + o];
    out[idx] = v > 0.f ? v : 0.f;
}

extern "C" void kernel_launch(void* const* d_in, const int* in_sizes, int n_in,
                              void* d_out, int out_size, void* d_ws, size_t ws_size,
                              hipStream_t stream) {
    const float* x      = (const float*)d_in[0];
    const float* lin_w  = (const float*)d_in[1];
    const float* lin_b  = (const float*)d_in[2];
    const float* a      = (const float*)d_in[3];
    const float* bias   = (const float*)d_in[4];
    const float* lin2_w = (const float*)d_in[5];
    const float* lin2_b = (const float*)d_in[6];

    float* out = (float*)d_out;
    float* h2  = out;                                  // B*F*OUT2
    float* att = out + (size_t)B_ * F_ * OUT2_;        // B*K*K

    // ws: 512 (unused, layout-preserving) | s1 32K | s2 32K | ht bf16 8MB |
    // xt bf16 8MB (reused as part). total 17,041,408 B == proven footprint.
    float* ws = (float*)d_ws;
    float* s1 = ws + 512;
    float* s2 = ws + 512 + B_ * K_;
    unsigned short* ht = (unsigned short*)(ws + 512 + 2 * B_ * K_);   // B*F*K bf16
    unsigned short* xt = ht + (size_t)B_ * K_ * F_;                   // B*K*F bf16
    float* part = (float*)xt;   // 4*32*128*128 floats = 8 MB; xt dead after k_attx

    k_xts<<<dim3(16, B_), 256, 0, stream>>>(x, lin_w, lin_b, a, xt, s1, s2);
    k_softmax<<<B_ * K_, 256, 0, stream>>>(s1, s2, bias, att);
    k_attx<<<dim3(K_ / 32, B_), 256, 0, stream>>>(att, xt, x, ht);
    k_out2m<<<dim3(2, B_, 4), 256, 0, stream>>>(ht, lin2_w, part);
    k_out2e<<<(B_ * F_ * OUT2_ + 255) / 256, 256, 0, stream>>>(part, lin2_b, h2);
}